// Round 1
// baseline (1564.773 us; speedup 1.0000x reference)
//
#include <hip/hip_runtime.h>

// ---------------- problem constants ----------------
constexpr int Nn = 100000;   // nodes
constexpr int Ee = 1600000;  // edges
// IN = 256, H = 64, NH = 4 (layer1 heads), head 4 = output head

// ---------------- workspace layout (bytes) ----------------
constexpr size_t O_ROWPTR = 0;              // (Nn+1) int
constexpr size_t O_COUNTS = 400512;         // Nn int
constexpr size_t O_CURSOR = 801024;         // Nn int
constexpr size_t O_BSUMS  = 1201536;        // 512 int
constexpr size_t O_CSRDST = 1203712;        // Ee int
constexpr size_t O_INV    = 7603712;        // Ee int
constexpr size_t O_FT1    = 14003712;       // Nn*256 f32
constexpr size_t O_LAST   = 116403712;      // Nn*256 f32
constexpr size_t O_A4     = 218803712;      // Ee*4 f32
constexpr size_t O_EACSR  = 244403712;      // Ee*4 f32
constexpr size_t O_M4     = 270003712;      // Nn*4 f32(uint)
constexpr size_t O_S4     = 271603712;      // Nn*4 f32
constexpr size_t O_A14    = 273203712;      // Nn*4 f32
constexpr size_t O_A24    = 274803712;      // Nn*4 f32
constexpr size_t O_M2     = 276403712;      // Nn f32(uint)
constexpr size_t O_S2     = 276804224;      // Nn f32
constexpr size_t O_A12    = 277204736;      // Nn f32
constexpr size_t O_A22    = 277605248;      // Nn f32
// aliases (lifetimes disjoint):
constexpr size_t O_FT2    = O_FT1;                    // Nn*64 f32
constexpr size_t O_OUT2   = O_FT1 + 25600000;         // Nn*64 f32
constexpr size_t O_AL2    = O_A4;                     // Ee f32
constexpr size_t O_EAL2   = O_EACSR;                  // Ee f32

// ---------------- CSR build ----------------
__global__ void count_k(const int* __restrict__ src, int* __restrict__ counts) {
    int e = blockIdx.x * 256 + threadIdx.x;
    if (e < Ee) atomicAdd(&counts[src[e]], 1);
}

__global__ void scan_local_k(const int* __restrict__ counts, int* __restrict__ rowp,
                             int* __restrict__ bsums) {
    __shared__ int sh[256];
    int t = threadIdx.x;
    int idx = blockIdx.x * 256 + t;
    int v = (idx < Nn) ? counts[idx] : 0;
    sh[t] = v;
    __syncthreads();
    for (int o = 1; o < 256; o <<= 1) {
        int x = (t >= o) ? sh[t - o] : 0;
        __syncthreads();
        sh[t] += x;
        __syncthreads();
    }
    if (idx < Nn) rowp[idx] = sh[t] - v;   // exclusive within block
    if (t == 255) bsums[blockIdx.x] = sh[t];
}

__global__ void scan_tot_k(int* __restrict__ bsums, int nb) {
    __shared__ int sh[512];
    int t = threadIdx.x;
    int v = (t < nb) ? bsums[t] : 0;
    sh[t] = v;
    __syncthreads();
    for (int o = 1; o < 512; o <<= 1) {
        int x = (t >= o) ? sh[t - o] : 0;
        __syncthreads();
        sh[t] += x;
        __syncthreads();
    }
    if (t < nb) bsums[t] = sh[t] - v;      // exclusive block offsets
}

__global__ void scan_add_k(int* __restrict__ rowp, const int* __restrict__ bsums,
                           int* __restrict__ cursor) {
    int idx = blockIdx.x * 256 + threadIdx.x;
    if (idx < Nn) {
        int r = rowp[idx] + bsums[blockIdx.x];
        rowp[idx] = r;
        cursor[idx] = r;
    }
    if (blockIdx.x == 0 && threadIdx.x == 0) rowp[Nn] = Ee;
}

__global__ void fill_k(const int* __restrict__ src, const int* __restrict__ dst,
                       int* __restrict__ cursor, int* __restrict__ csr_dst,
                       int* __restrict__ inv) {
    int e = blockIdx.x * 256 + threadIdx.x;
    if (e >= Ee) return;
    int s = src[e];
    int pos = atomicAdd(&cursor[s], 1);
    csr_dst[pos] = dst[e];
    inv[e] = pos;
}

// ---------------- GEMM: C[N,ncols] = X[N,256] @ W[256,64(per head)] + b ----------------
template <int ELU, int ADD>
__global__ __launch_bounds__(256) void gemm_k(const float* __restrict__ X,
                                              const float* __restrict__ W, int whstride,
                                              const float* __restrict__ bias, int bhstride,
                                              const float* __restrict__ addp,
                                              float* __restrict__ out, int orstride) {
    __shared__ float As[64][65];
    __shared__ float Ws[64][64];
    int tid = threadIdx.x;
    int head = blockIdx.y;
    const float* Wp = W + (size_t)head * whstride;
    const float* bp = bias + (size_t)head * bhstride;
    int m0 = blockIdx.x * 64;
    int trow = tid >> 4, tcol = tid & 15;
    float acc[4][4] = {};
    for (int kc = 0; kc < 4; ++kc) {
        int k0 = kc * 64;
#pragma unroll
        for (int t = 0; t < 4; ++t) {
            int f4 = tid + t * 256;
            int row = f4 >> 4, c4 = f4 & 15;
            int r = m0 + row;
            float4 av = (r < Nn) ? *(const float4*)(X + (size_t)r * 256 + k0 + c4 * 4)
                                 : make_float4(0.f, 0.f, 0.f, 0.f);
            As[row][c4 * 4 + 0] = av.x;
            As[row][c4 * 4 + 1] = av.y;
            As[row][c4 * 4 + 2] = av.z;
            As[row][c4 * 4 + 3] = av.w;
            float4 wv = *(const float4*)(Wp + (size_t)(k0 + row) * 64 + c4 * 4);
            *(float4*)&Ws[row][c4 * 4] = wv;
        }
        __syncthreads();
#pragma unroll 8
        for (int k = 0; k < 64; ++k) {
            float a0 = As[trow * 4 + 0][k];
            float a1 = As[trow * 4 + 1][k];
            float a2 = As[trow * 4 + 2][k];
            float a3 = As[trow * 4 + 3][k];
            float4 w = *(float4*)&Ws[k][tcol * 4];
            acc[0][0] += a0 * w.x; acc[0][1] += a0 * w.y; acc[0][2] += a0 * w.z; acc[0][3] += a0 * w.w;
            acc[1][0] += a1 * w.x; acc[1][1] += a1 * w.y; acc[1][2] += a1 * w.z; acc[1][3] += a1 * w.w;
            acc[2][0] += a2 * w.x; acc[2][1] += a2 * w.y; acc[2][2] += a2 * w.z; acc[2][3] += a2 * w.w;
            acc[3][0] += a3 * w.x; acc[3][1] += a3 * w.y; acc[3][2] += a3 * w.z; acc[3][3] += a3 * w.w;
        }
        __syncthreads();
    }
    float4 b4 = *(const float4*)(bp + tcol * 4);
#pragma unroll
    for (int i = 0; i < 4; ++i) {
        int r = m0 + trow * 4 + i;
        if (r < Nn) {
            float v0 = acc[i][0] + b4.x;
            float v1 = acc[i][1] + b4.y;
            float v2 = acc[i][2] + b4.z;
            float v3 = acc[i][3] + b4.w;
            if (ADD) {
                float4 ad = *(const float4*)(addp + (size_t)r * 64 + tcol * 4);
                v0 += ad.x; v1 += ad.y; v2 += ad.z; v3 += ad.w;
            }
            if (ELU) {
                v0 = v0 > 0.f ? v0 : __expf(v0) - 1.f;
                v1 = v1 > 0.f ? v1 : __expf(v1) - 1.f;
                v2 = v2 > 0.f ? v2 : __expf(v2) - 1.f;
                v3 = v3 > 0.f ? v3 : __expf(v3) - 1.f;
            }
            float4 o4 = make_float4(v0, v1, v2, v3);
            *(float4*)(out + (size_t)r * orstride + head * 64 + tcol * 4) = o4;
        }
    }
}

// ---------------- per-node attention logits a1 = ft@wl+bl, a2 = ft@wr+br ----------------
template <int HN>
__global__ void a1a2_k(const float* __restrict__ ft, int rstride,
                       const float* __restrict__ wl, const float* __restrict__ bl,
                       const float* __restrict__ wr, const float* __restrict__ br,
                       float* __restrict__ a1, float* __restrict__ a2) {
    int node = blockIdx.x * 4 + (threadIdx.x >> 6);
    int lane = threadIdx.x & 63;
    if (node >= Nn) return;
#pragma unroll
    for (int h = 0; h < HN; ++h) {
        float x = ft[(size_t)node * rstride + h * 64 + lane];
        float s1 = x * wl[h * 64 + lane];
        float s2 = x * wr[h * 64 + lane];
        for (int o = 32; o; o >>= 1) {
            s1 += __shfl_xor(s1, o);
            s2 += __shfl_xor(s2, o);
        }
        if (lane == 0) {
            a1[node * HN + h] = s1 + bl[h];
            a2[node * HN + h] = s2 + br[h];
        }
    }
}

// ---------------- edge pass A: score + per-dst max (clamped at 0 via init) ----------------
template <int HN>
__global__ void edgeA_k(const int* __restrict__ src, const int* __restrict__ dst,
                        const float* __restrict__ a1, const float* __restrict__ a2,
                        float* __restrict__ aout, unsigned int* __restrict__ mmax) {
    int e = blockIdx.x * 256 + threadIdx.x;
    if (e >= Ee) return;
    int s = src[e], d = dst[e];
#pragma unroll
    for (int h = 0; h < HN; ++h) {
        float v = a1[d * HN + h] + a2[s * HN + h];
        float a = v > 0.f ? v : 0.01f * v;   // leaky_relu slope 0.01
        aout[(size_t)e * HN + h] = a;
        if (a > 0.f) atomicMax(&mmax[d * HN + h], __float_as_uint(a));
    }
}

// ---------------- edge pass B: exp, scatter to CSR slot, per-src sum ----------------
template <int HN>
__global__ void edgeB_k(const int* __restrict__ src, const int* __restrict__ dst,
                        const int* __restrict__ inv, const float* __restrict__ a,
                        const unsigned int* __restrict__ mmax,
                        float* __restrict__ eacsr, float* __restrict__ Ssum) {
    int e = blockIdx.x * 256 + threadIdx.x;
    if (e >= Ee) return;
    int s = src[e], d = dst[e], pos = inv[e];
#pragma unroll
    for (int h = 0; h < HN; ++h) {
        float m = __uint_as_float(mmax[d * HN + h]);
        float ea = __expf(a[(size_t)e * HN + h] - m);
        eacsr[(size_t)pos * HN + h] = ea;
        atomicAdd(&Ssum[s * HN + h], ea);
    }
}

// ---------------- edge pass C (layer 1, 4 heads): out[src] += (ea/S[dst]) * ft[dst], ELU ----------------
__global__ __launch_bounds__(256) void edgeC4_k(const int* __restrict__ rowp,
                                                const int* __restrict__ cdst,
                                                const float* __restrict__ eacsr,
                                                const float* __restrict__ S4,
                                                const float* __restrict__ ft,
                                                float* __restrict__ lastp) {
    int node = blockIdx.x * 4 + (threadIdx.x >> 6);
    int lane = threadIdx.x & 63;
    int h = lane >> 4;  // 4 channels per lane -> head = lane/16
    int r0 = rowp[node], r1 = rowp[node + 1];
    float ax = 0.f, ay = 0.f, az = 0.f, aw = 0.f;
    for (int i = r0; i < r1; ++i) {
        int d = cdst[i];
        float w = __fdividef(eacsr[(size_t)i * 4 + h], S4[d * 4 + h]);
        float4 f = *(const float4*)(ft + (size_t)d * 256 + lane * 4);
        ax += w * f.x; ay += w * f.y; az += w * f.z; aw += w * f.w;
    }
    ax = ax > 0.f ? ax : __expf(ax) - 1.f;
    ay = ay > 0.f ? ay : __expf(ay) - 1.f;
    az = az > 0.f ? az : __expf(az) - 1.f;
    aw = aw > 0.f ? aw : __expf(aw) - 1.f;
    *(float4*)(lastp + (size_t)node * 256 + lane * 4) = make_float4(ax, ay, az, aw);
}

// ---------------- edge pass C (layer 2, 1 head): raw aggregation ----------------
__global__ __launch_bounds__(256) void edgeC1_k(const int* __restrict__ rowp,
                                                const int* __restrict__ cdst,
                                                const float* __restrict__ ea,
                                                const float* __restrict__ S2,
                                                const float* __restrict__ ft,
                                                float* __restrict__ outp) {
    int node = blockIdx.x * 4 + (threadIdx.x >> 6);
    int lane = threadIdx.x & 63;
    int r0 = rowp[node], r1 = rowp[node + 1];
    float acc = 0.f;
    for (int i = r0; i < r1; ++i) {
        int d = cdst[i];
        float w = __fdividef(ea[i], S2[d]);
        acc += w * ft[(size_t)d * 64 + lane];
    }
    outp[(size_t)node * 64 + lane] = acc;
}

// ---------------- launch ----------------
extern "C" void kernel_launch(void* const* d_in, const int* in_sizes, int n_in,
                              void* d_out, int out_size, void* d_ws, size_t ws_size,
                              hipStream_t stream) {
    const float* features = (const float*)d_in[0];
    const int* src = (const int*)d_in[1];
    const int* dst = (const int*)d_in[2];
    const float* W_fc = (const float*)d_in[3];
    const float* b_fc = (const float*)d_in[4];
    const float* w_al = (const float*)d_in[5];
    const float* b_al = (const float*)d_in[6];
    const float* w_ar = (const float*)d_in[7];
    const float* b_ar = (const float*)d_in[8];
    const float* W_res = (const float*)d_in[9];
    const float* b_res = (const float*)d_in[10];
    float* out = (float*)d_out;
    char* ws = (char*)d_ws;

    int* rowp = (int*)(ws + O_ROWPTR);
    int* counts = (int*)(ws + O_COUNTS);
    int* cursor = (int*)(ws + O_CURSOR);
    int* bsums = (int*)(ws + O_BSUMS);
    int* csr_dst = (int*)(ws + O_CSRDST);
    int* inv = (int*)(ws + O_INV);
    float* ft1 = (float*)(ws + O_FT1);
    float* last = (float*)(ws + O_LAST);
    float* a4 = (float*)(ws + O_A4);
    float* eacsr = (float*)(ws + O_EACSR);
    unsigned int* m4 = (unsigned int*)(ws + O_M4);
    float* S4 = (float*)(ws + O_S4);
    float* a1_4 = (float*)(ws + O_A14);
    float* a2_4 = (float*)(ws + O_A24);
    unsigned int* m2 = (unsigned int*)(ws + O_M2);
    float* S2 = (float*)(ws + O_S2);
    float* a1_2 = (float*)(ws + O_A12);
    float* a2_2 = (float*)(ws + O_A22);
    float* ft2 = (float*)(ws + O_FT2);
    float* out2 = (float*)(ws + O_OUT2);
    float* a_l2 = (float*)(ws + O_AL2);
    float* ea_l2 = (float*)(ws + O_EAL2);

    hipMemsetAsync(counts, 0, (size_t)Nn * 4, stream);
    hipMemsetAsync(m4, 0, (size_t)Nn * 16, stream);
    hipMemsetAsync(S4, 0, (size_t)Nn * 16, stream);
    hipMemsetAsync(m2, 0, (size_t)Nn * 4, stream);
    hipMemsetAsync(S2, 0, (size_t)Nn * 4, stream);

    constexpr int NB = (Nn + 255) / 256;  // 391
    count_k<<<(Ee + 255) / 256, 256, 0, stream>>>(src, counts);
    scan_local_k<<<NB, 256, 0, stream>>>(counts, rowp, bsums);
    scan_tot_k<<<1, 512, 0, stream>>>(bsums, NB);
    scan_add_k<<<NB, 256, 0, stream>>>(rowp, bsums, cursor);
    fill_k<<<(Ee + 255) / 256, 256, 0, stream>>>(src, dst, cursor, csr_dst, inv);

    const int MB = (Nn + 63) / 64;  // 1563
    // ---- layer 1: 4 heads ----
    gemm_k<0, 0><<<dim3(MB, 4), 256, 0, stream>>>(features, W_fc, 256 * 64, b_fc, 64,
                                                  nullptr, ft1, 256);
    a1a2_k<4><<<Nn / 4, 256, 0, stream>>>(ft1, 256, w_al, b_al, w_ar, b_ar, a1_4, a2_4);
    edgeA_k<4><<<(Ee + 255) / 256, 256, 0, stream>>>(src, dst, a1_4, a2_4, a4, m4);
    edgeB_k<4><<<(Ee + 255) / 256, 256, 0, stream>>>(src, dst, inv, a4, m4, eacsr, S4);
    edgeC4_k<<<Nn / 4, 256, 0, stream>>>(rowp, csr_dst, eacsr, S4, ft1, last);

    // ---- layer 2: head 4 ----
    gemm_k<0, 0><<<dim3(MB, 1), 256, 0, stream>>>(last, W_fc + 4 * 256 * 64, 0,
                                                  b_fc + 4 * 64, 0, nullptr, ft2, 64);
    a1a2_k<1><<<Nn / 4, 256, 0, stream>>>(ft2, 64, w_al + 4 * 64, b_al + 4,
                                          w_ar + 4 * 64, b_ar + 4, a1_2, a2_2);
    edgeA_k<1><<<(Ee + 255) / 256, 256, 0, stream>>>(src, dst, a1_2, a2_2, a_l2, m2);
    edgeB_k<1><<<(Ee + 255) / 256, 256, 0, stream>>>(src, dst, inv, a_l2, m2, ea_l2, S2);
    edgeC1_k<<<Nn / 4, 256, 0, stream>>>(rowp, csr_dst, ea_l2, S2, ft2, out2);

    // ---- final: elu(last @ W_res + b_res + out2) ----
    gemm_k<1, 1><<<dim3(MB, 1), 256, 0, stream>>>(last, W_res, 0, b_res, 0, out2, out, 64);
}

// Round 2
// 1263.652 us; speedup vs baseline: 1.2383x; 1.2383x over previous
//
#include <hip/hip_runtime.h>

// ---------------- problem constants ----------------
constexpr int Nn = 100000;   // nodes
constexpr int Ee = 1600000;  // edges
// IN = 256, H = 64, NH = 4 (layer1 heads), head 4 = output head

// ---------------- workspace layout (bytes) ----------------
constexpr size_t O_ROWPS  = 0;              // (Nn+1) int   CSR (by src) rowptr
constexpr size_t O_ROWPD  = 400512;         // (Nn+1) int   CSC (by dst) rowptr
constexpr size_t O_CNTS   = 801024;         // Nn int
constexpr size_t O_CNTD   = 1201536;        // Nn int
constexpr size_t O_CURSOR = 1602048;        // Nn int
constexpr size_t O_BSUMS  = 2002560;        // 512 int
constexpr size_t O_CSRDST = 2004608;        // Ee int  (dst per slot, src-sorted)
constexpr size_t O_CSCSRC = 8404608;        // Ee int  (src per slot, dst-sorted)
constexpr size_t O_FT1    = 14804608;       // Nn*256 f32
constexpr size_t O_LAST   = 117204608;      // Nn*256 f32
constexpr size_t O_EACSR  = 219604608;      // Ee*4 f32 (layer1) / Ee f32 (layer2 alias)
constexpr size_t O_M4     = 245204608;      // Nn*4 f32
constexpr size_t O_S4     = 246804608;      // Nn*4 f32
constexpr size_t O_A14    = 248404608;      // Nn*4 f32
constexpr size_t O_A24    = 250004608;      // Nn*4 f32
constexpr size_t O_M2     = 251604608;      // Nn f32
constexpr size_t O_S2     = 252004608;      // Nn f32
constexpr size_t O_A12    = 252404608;      // Nn f32
constexpr size_t O_A22    = 252804608;      // Nn f32
// aliases (lifetimes disjoint):
constexpr size_t O_FT2    = O_FT1;                    // Nn*64 f32
constexpr size_t O_OUT2   = O_FT1 + 25600000;         // Nn*64 f32
constexpr size_t O_EAL2   = O_EACSR;                  // Ee f32

// ---------------- CSR/CSC build ----------------
__global__ void count_k(const int* __restrict__ key, int* __restrict__ counts) {
    int e = blockIdx.x * 256 + threadIdx.x;
    if (e < Ee) atomicAdd(&counts[key[e]], 1);
}

__global__ void scan_local_k(const int* __restrict__ counts, int* __restrict__ rowp,
                             int* __restrict__ bsums) {
    __shared__ int sh[256];
    int t = threadIdx.x;
    int idx = blockIdx.x * 256 + t;
    int v = (idx < Nn) ? counts[idx] : 0;
    sh[t] = v;
    __syncthreads();
    for (int o = 1; o < 256; o <<= 1) {
        int x = (t >= o) ? sh[t - o] : 0;
        __syncthreads();
        sh[t] += x;
        __syncthreads();
    }
    if (idx < Nn) rowp[idx] = sh[t] - v;   // exclusive within block
    if (t == 255) bsums[blockIdx.x] = sh[t];
}

__global__ void scan_tot_k(int* __restrict__ bsums, int nb) {
    __shared__ int sh[512];
    int t = threadIdx.x;
    int v = (t < nb) ? bsums[t] : 0;
    sh[t] = v;
    __syncthreads();
    for (int o = 1; o < 512; o <<= 1) {
        int x = (t >= o) ? sh[t - o] : 0;
        __syncthreads();
        sh[t] += x;
        __syncthreads();
    }
    if (t < nb) bsums[t] = sh[t] - v;      // exclusive block offsets
}

__global__ void scan_add_k(int* __restrict__ rowp, const int* __restrict__ bsums,
                           int* __restrict__ cursor) {
    int idx = blockIdx.x * 256 + threadIdx.x;
    if (idx < Nn) {
        int r = rowp[idx] + bsums[blockIdx.x];
        rowp[idx] = r;
        cursor[idx] = r;
    }
    if (blockIdx.x == 0 && threadIdx.x == 0) rowp[Nn] = Ee;
}

__global__ void fillv_k(const int* __restrict__ key, const int* __restrict__ val,
                        int* __restrict__ cursor, int* __restrict__ outv) {
    int e = blockIdx.x * 256 + threadIdx.x;
    if (e >= Ee) return;
    int pos = atomicAdd(&cursor[key[e]], 1);
    outv[pos] = val[e];
}

// ---------------- GEMM: C[N,ncols] = X[N,256] @ W[256,64(per head)] + b ----------------
template <int ELU, int ADD>
__global__ __launch_bounds__(256) void gemm_k(const float* __restrict__ X,
                                              const float* __restrict__ W, int whstride,
                                              const float* __restrict__ bias, int bhstride,
                                              const float* __restrict__ addp,
                                              float* __restrict__ out, int orstride) {
    __shared__ float As[64][65];
    __shared__ float Ws[64][64];
    int tid = threadIdx.x;
    int head = blockIdx.y;
    const float* Wp = W + (size_t)head * whstride;
    const float* bp = bias + (size_t)head * bhstride;
    int m0 = blockIdx.x * 64;
    int trow = tid >> 4, tcol = tid & 15;
    float acc[4][4] = {};
    for (int kc = 0; kc < 4; ++kc) {
        int k0 = kc * 64;
#pragma unroll
        for (int t = 0; t < 4; ++t) {
            int f4 = tid + t * 256;
            int row = f4 >> 4, c4 = f4 & 15;
            int r = m0 + row;
            float4 av = (r < Nn) ? *(const float4*)(X + (size_t)r * 256 + k0 + c4 * 4)
                                 : make_float4(0.f, 0.f, 0.f, 0.f);
            As[row][c4 * 4 + 0] = av.x;
            As[row][c4 * 4 + 1] = av.y;
            As[row][c4 * 4 + 2] = av.z;
            As[row][c4 * 4 + 3] = av.w;
            float4 wv = *(const float4*)(Wp + (size_t)(k0 + row) * 64 + c4 * 4);
            *(float4*)&Ws[row][c4 * 4] = wv;
        }
        __syncthreads();
#pragma unroll 8
        for (int k = 0; k < 64; ++k) {
            float a0 = As[trow * 4 + 0][k];
            float a1 = As[trow * 4 + 1][k];
            float a2 = As[trow * 4 + 2][k];
            float a3 = As[trow * 4 + 3][k];
            float4 w = *(float4*)&Ws[k][tcol * 4];
            acc[0][0] += a0 * w.x; acc[0][1] += a0 * w.y; acc[0][2] += a0 * w.z; acc[0][3] += a0 * w.w;
            acc[1][0] += a1 * w.x; acc[1][1] += a1 * w.y; acc[1][2] += a1 * w.z; acc[1][3] += a1 * w.w;
            acc[2][0] += a2 * w.x; acc[2][1] += a2 * w.y; acc[2][2] += a2 * w.z; acc[2][3] += a2 * w.w;
            acc[3][0] += a3 * w.x; acc[3][1] += a3 * w.y; acc[3][2] += a3 * w.z; acc[3][3] += a3 * w.w;
        }
        __syncthreads();
    }
    float4 b4 = *(const float4*)(bp + tcol * 4);
#pragma unroll
    for (int i = 0; i < 4; ++i) {
        int r = m0 + trow * 4 + i;
        if (r < Nn) {
            float v0 = acc[i][0] + b4.x;
            float v1 = acc[i][1] + b4.y;
            float v2 = acc[i][2] + b4.z;
            float v3 = acc[i][3] + b4.w;
            if (ADD) {
                float4 ad = *(const float4*)(addp + (size_t)r * 64 + tcol * 4);
                v0 += ad.x; v1 += ad.y; v2 += ad.z; v3 += ad.w;
            }
            if (ELU) {
                v0 = v0 > 0.f ? v0 : __expf(v0) - 1.f;
                v1 = v1 > 0.f ? v1 : __expf(v1) - 1.f;
                v2 = v2 > 0.f ? v2 : __expf(v2) - 1.f;
                v3 = v3 > 0.f ? v3 : __expf(v3) - 1.f;
            }
            float4 o4 = make_float4(v0, v1, v2, v3);
            *(float4*)(out + (size_t)r * orstride + head * 64 + tcol * 4) = o4;
        }
    }
}

// ---------------- per-node attention logits a1 = ft@wl+bl, a2 = ft@wr+br ----------------
template <int HN>
__global__ void a1a2_k(const float* __restrict__ ft, int rstride,
                       const float* __restrict__ wl, const float* __restrict__ bl,
                       const float* __restrict__ wr, const float* __restrict__ br,
                       float* __restrict__ a1, float* __restrict__ a2) {
    int node = blockIdx.x * 4 + (threadIdx.x >> 6);
    int lane = threadIdx.x & 63;
    if (node >= Nn) return;
#pragma unroll
    for (int h = 0; h < HN; ++h) {
        float x = ft[(size_t)node * rstride + h * 64 + lane];
        float s1 = x * wl[h * 64 + lane];
        float s2 = x * wr[h * 64 + lane];
        for (int o = 32; o; o >>= 1) {
            s1 += __shfl_xor(s1, o);
            s2 += __shfl_xor(s2, o);
        }
        if (lane == 0) {
            a1[node * HN + h] = s1 + bl[h];
            a2[node * HN + h] = s2 + br[h];
        }
    }
}

// ---------------- max pass (CSC walk): m[d] = max(0, max_e leaky(a1[d]+a2[src])) ----------------
__global__ __launch_bounds__(256) void maxpass4_k(const int* __restrict__ rowpd,
                                                  const int* __restrict__ cscsrc,
                                                  const float* __restrict__ a1,
                                                  const float* __restrict__ a2,
                                                  float* __restrict__ mmax) {
    int node = blockIdx.x * 4 + (threadIdx.x >> 6);
    int lane = threadIdx.x & 63;
    if (node >= Nn) return;
    int h = lane & 3, ei = lane >> 2;
    int r0 = rowpd[node], r1 = rowpd[node + 1];
    float a1v = a1[node * 4 + h];
    float m = 0.f;
    for (int i = r0 + ei; i < r1; i += 16) {
        int s = cscsrc[i];
        float v = a1v + a2[s * 4 + h];
        float a = v > 0.f ? v : 0.01f * v;
        m = fmaxf(m, a);
    }
#pragma unroll
    for (int o = 4; o < 64; o <<= 1) m = fmaxf(m, __shfl_xor(m, o));
    if (lane < 4) mmax[node * 4 + lane] = m;
}

__global__ __launch_bounds__(256) void maxpass1_k(const int* __restrict__ rowpd,
                                                  const int* __restrict__ cscsrc,
                                                  const float* __restrict__ a1,
                                                  const float* __restrict__ a2,
                                                  float* __restrict__ mmax) {
    int node = blockIdx.x * 4 + (threadIdx.x >> 6);
    int lane = threadIdx.x & 63;
    if (node >= Nn) return;
    int r0 = rowpd[node], r1 = rowpd[node + 1];
    float a1v = a1[node];
    float m = 0.f;
    for (int i = r0 + lane; i < r1; i += 64) {
        float v = a1v + a2[cscsrc[i]];
        float a = v > 0.f ? v : 0.01f * v;
        m = fmaxf(m, a);
    }
#pragma unroll
    for (int o = 1; o < 64; o <<= 1) m = fmaxf(m, __shfl_xor(m, o));
    if (lane == 0) mmax[node] = m;
}

// ---------------- sum pass (CSR walk): ea[i]=exp(a-m[dst]); S[s]=sum ----------------
__global__ __launch_bounds__(256) void sumpass4_k(const int* __restrict__ rowps,
                                                  const int* __restrict__ csrdst,
                                                  const float* __restrict__ a1,
                                                  const float* __restrict__ a2,
                                                  const float* __restrict__ mmax,
                                                  float* __restrict__ eacsr,
                                                  float* __restrict__ Ssum) {
    int node = blockIdx.x * 4 + (threadIdx.x >> 6);
    int lane = threadIdx.x & 63;
    if (node >= Nn) return;
    int h = lane & 3, ei = lane >> 2;
    int r0 = rowps[node], r1 = rowps[node + 1];
    float a2v = a2[node * 4 + h];
    float S = 0.f;
    for (int i = r0 + ei; i < r1; i += 16) {
        int d = csrdst[i];
        float v = a1[d * 4 + h] + a2v;
        float a = v > 0.f ? v : 0.01f * v;
        float ea = __expf(a - mmax[d * 4 + h]);
        eacsr[(size_t)i * 4 + h] = ea;
        S += ea;
    }
#pragma unroll
    for (int o = 4; o < 64; o <<= 1) S += __shfl_xor(S, o);
    if (lane < 4) Ssum[node * 4 + lane] = S;
}

__global__ __launch_bounds__(256) void sumpass1_k(const int* __restrict__ rowps,
                                                  const int* __restrict__ csrdst,
                                                  const float* __restrict__ a1,
                                                  const float* __restrict__ a2,
                                                  const float* __restrict__ mmax,
                                                  float* __restrict__ eacsr,
                                                  float* __restrict__ Ssum) {
    int node = blockIdx.x * 4 + (threadIdx.x >> 6);
    int lane = threadIdx.x & 63;
    if (node >= Nn) return;
    int r0 = rowps[node], r1 = rowps[node + 1];
    float a2v = a2[node];
    float S = 0.f;
    for (int i = r0 + lane; i < r1; i += 64) {
        int d = csrdst[i];
        float v = a1[d] + a2v;
        float a = v > 0.f ? v : 0.01f * v;
        float ea = __expf(a - mmax[d]);
        eacsr[i] = ea;
        S += ea;
    }
#pragma unroll
    for (int o = 1; o < 64; o <<= 1) S += __shfl_xor(S, o);
    if (lane == 0) Ssum[node] = S;
}

// ---------------- edge pass C (layer 1, 4 heads): out[src] = sum (ea/S[dst]) * ft[dst], ELU ----------------
__global__ __launch_bounds__(256) void edgeC4_k(const int* __restrict__ rowp,
                                                const int* __restrict__ cdst,
                                                const float* __restrict__ eacsr,
                                                const float* __restrict__ S4,
                                                const float* __restrict__ ft,
                                                float* __restrict__ lastp) {
    int node = blockIdx.x * 4 + (threadIdx.x >> 6);
    int lane = threadIdx.x & 63;
    if (node >= Nn) return;
    int h = lane >> 4;  // 4 channels per lane -> head = lane/16
    int r0 = rowp[node], r1 = rowp[node + 1];
    float ax = 0.f, ay = 0.f, az = 0.f, aw = 0.f;
    for (int i = r0; i < r1; ++i) {
        int d = cdst[i];
        float w = __fdividef(eacsr[(size_t)i * 4 + h], S4[d * 4 + h]);
        float4 f = *(const float4*)(ft + (size_t)d * 256 + lane * 4);
        ax += w * f.x; ay += w * f.y; az += w * f.z; aw += w * f.w;
    }
    ax = ax > 0.f ? ax : __expf(ax) - 1.f;
    ay = ay > 0.f ? ay : __expf(ay) - 1.f;
    az = az > 0.f ? az : __expf(az) - 1.f;
    aw = aw > 0.f ? aw : __expf(aw) - 1.f;
    *(float4*)(lastp + (size_t)node * 256 + lane * 4) = make_float4(ax, ay, az, aw);
}

// ---------------- edge pass C (layer 2, 1 head): raw aggregation ----------------
__global__ __launch_bounds__(256) void edgeC1_k(const int* __restrict__ rowp,
                                                const int* __restrict__ cdst,
                                                const float* __restrict__ ea,
                                                const float* __restrict__ S2,
                                                const float* __restrict__ ft,
                                                float* __restrict__ outp) {
    int node = blockIdx.x * 4 + (threadIdx.x >> 6);
    int lane = threadIdx.x & 63;
    if (node >= Nn) return;
    int r0 = rowp[node], r1 = rowp[node + 1];
    float acc = 0.f;
    for (int i = r0; i < r1; ++i) {
        int d = cdst[i];
        float w = __fdividef(ea[i], S2[d]);
        acc += w * ft[(size_t)d * 64 + lane];
    }
    outp[(size_t)node * 64 + lane] = acc;
}

// ---------------- launch ----------------
extern "C" void kernel_launch(void* const* d_in, const int* in_sizes, int n_in,
                              void* d_out, int out_size, void* d_ws, size_t ws_size,
                              hipStream_t stream) {
    const float* features = (const float*)d_in[0];
    const int* src = (const int*)d_in[1];
    const int* dst = (const int*)d_in[2];
    const float* W_fc = (const float*)d_in[3];
    const float* b_fc = (const float*)d_in[4];
    const float* w_al = (const float*)d_in[5];
    const float* b_al = (const float*)d_in[6];
    const float* w_ar = (const float*)d_in[7];
    const float* b_ar = (const float*)d_in[8];
    const float* W_res = (const float*)d_in[9];
    const float* b_res = (const float*)d_in[10];
    float* out = (float*)d_out;
    char* ws = (char*)d_ws;

    int* rowps = (int*)(ws + O_ROWPS);
    int* rowpd = (int*)(ws + O_ROWPD);
    int* cnts = (int*)(ws + O_CNTS);
    int* cntd = (int*)(ws + O_CNTD);
    int* cursor = (int*)(ws + O_CURSOR);
    int* bsums = (int*)(ws + O_BSUMS);
    int* csr_dst = (int*)(ws + O_CSRDST);
    int* csc_src = (int*)(ws + O_CSCSRC);
    float* ft1 = (float*)(ws + O_FT1);
    float* last = (float*)(ws + O_LAST);
    float* eacsr = (float*)(ws + O_EACSR);
    float* m4 = (float*)(ws + O_M4);
    float* S4 = (float*)(ws + O_S4);
    float* a1_4 = (float*)(ws + O_A14);
    float* a2_4 = (float*)(ws + O_A24);
    float* m2 = (float*)(ws + O_M2);
    float* S2 = (float*)(ws + O_S2);
    float* a1_2 = (float*)(ws + O_A12);
    float* a2_2 = (float*)(ws + O_A22);
    float* ft2 = (float*)(ws + O_FT2);
    float* out2 = (float*)(ws + O_OUT2);
    float* ea_l2 = (float*)(ws + O_EAL2);

    hipMemsetAsync(cnts, 0, (size_t)Nn * 4, stream);
    hipMemsetAsync(cntd, 0, (size_t)Nn * 4, stream);

    constexpr int NB = (Nn + 255) / 256;  // 391
    constexpr int EB = (Ee + 255) / 256;
    // CSR by src (values = dst)
    count_k<<<EB, 256, 0, stream>>>(src, cnts);
    scan_local_k<<<NB, 256, 0, stream>>>(cnts, rowps, bsums);
    scan_tot_k<<<1, 512, 0, stream>>>(bsums, NB);
    scan_add_k<<<NB, 256, 0, stream>>>(rowps, bsums, cursor);
    fillv_k<<<EB, 256, 0, stream>>>(src, dst, cursor, csr_dst);
    // CSC by dst (values = src)
    count_k<<<EB, 256, 0, stream>>>(dst, cntd);
    scan_local_k<<<NB, 256, 0, stream>>>(cntd, rowpd, bsums);
    scan_tot_k<<<1, 512, 0, stream>>>(bsums, NB);
    scan_add_k<<<NB, 256, 0, stream>>>(rowpd, bsums, cursor);
    fillv_k<<<EB, 256, 0, stream>>>(dst, src, cursor, csc_src);

    const int MB = (Nn + 63) / 64;  // 1563
    const int NW = (Nn + 3) / 4;    // 25000 (4 node-waves per block)
    // ---- layer 1: 4 heads ----
    gemm_k<0, 0><<<dim3(MB, 4), 256, 0, stream>>>(features, W_fc, 256 * 64, b_fc, 64,
                                                  nullptr, ft1, 256);
    a1a2_k<4><<<NW, 256, 0, stream>>>(ft1, 256, w_al, b_al, w_ar, b_ar, a1_4, a2_4);
    maxpass4_k<<<NW, 256, 0, stream>>>(rowpd, csc_src, a1_4, a2_4, m4);
    sumpass4_k<<<NW, 256, 0, stream>>>(rowps, csr_dst, a1_4, a2_4, m4, eacsr, S4);
    edgeC4_k<<<NW, 256, 0, stream>>>(rowps, csr_dst, eacsr, S4, ft1, last);

    // ---- layer 2: head 4 ----
    gemm_k<0, 0><<<dim3(MB, 1), 256, 0, stream>>>(last, W_fc + 4 * 256 * 64, 0,
                                                  b_fc + 4 * 64, 0, nullptr, ft2, 64);
    a1a2_k<1><<<NW, 256, 0, stream>>>(ft2, 64, w_al + 4 * 64, b_al + 4,
                                      w_ar + 4 * 64, b_ar + 4, a1_2, a2_2);
    maxpass1_k<<<NW, 256, 0, stream>>>(rowpd, csc_src, a1_2, a2_2, m2);
    sumpass1_k<<<NW, 256, 0, stream>>>(rowps, csr_dst, a1_2, a2_2, m2, ea_l2, S2);
    edgeC1_k<<<NW, 256, 0, stream>>>(rowps, csr_dst, ea_l2, S2, ft2, out2);

    // ---- final: elu(last @ W_res + b_res + out2) ----
    gemm_k<1, 1><<<dim3(MB, 1), 256, 0, stream>>>(last, W_res, 0, b_res, 0, out2, out, 64);
}

// Round 3
// 1134.633 us; speedup vs baseline: 1.3791x; 1.1137x over previous
//
#include <hip/hip_runtime.h>

typedef unsigned short ushort_t;

// ---------------- problem constants ----------------
constexpr int Nn = 100000;   // nodes
constexpr int Ee = 1600000;  // edges
// IN = 256, H = 64, NH = 4 (layer1 heads), head 4 = output head

// ---------------- workspace layout (bytes) ----------------
constexpr size_t O_ROWPS  = 0;              // (Nn+1) int   CSR (by src) rowptr
constexpr size_t O_ROWPD  = 400512;         // (Nn+1) int   CSC (by dst) rowptr
constexpr size_t O_CNTS   = 801024;         // Nn int   (cnts+cntd contiguous -> one memset)
constexpr size_t O_CNTD   = 1201536;        // Nn int
constexpr size_t O_CURS   = 1602048;        // Nn int
constexpr size_t O_CURD   = 2002560;        // Nn int
constexpr size_t O_BSUMS  = 2403072;        // 512 int
constexpr size_t O_CSRDST = 2405632;        // Ee int  (dst per slot, src-sorted)
constexpr size_t O_CSCSRC = 8805632;        // Ee int  (src per slot, dst-sorted)
constexpr size_t O_FTB1   = 15205632;       // Nn*256 bf16 (51.2MB)
constexpr size_t O_FTB2   = 66405632;       // Nn*64 bf16 (12.8MB)
constexpr size_t O_LAST   = 79205632;       // Nn*256 f32 (102.4MB)
constexpr size_t O_EACSR  = 181605632;      // Ee*4 f32 (layer1) / Ee f32 (layer2 alias)
constexpr size_t O_M4     = 207205632;      // Nn*4 f32
constexpr size_t O_S4     = 208805632;      // Nn*4 f32
constexpr size_t O_A14    = 210405632;      // Nn*4 f32
constexpr size_t O_A24    = 212005632;      // Nn*4 f32
constexpr size_t O_M2     = 213605632;      // Nn f32
constexpr size_t O_S2     = 214006144;      // Nn f32
constexpr size_t O_A12    = 214406656;      // Nn f32
constexpr size_t O_A22    = 214807168;      // Nn f32
constexpr size_t O_OUT2   = 215207680;      // Nn*64 f32 (25.6MB)  end ~240.8MB
constexpr size_t O_EAL2   = O_EACSR;        // Ee f32 alias

__device__ __forceinline__ ushort_t f2bf(float x) {
    unsigned u = __float_as_uint(x);
    unsigned r = (u + 0x7FFFu + ((u >> 16) & 1u)) >> 16;
    return (ushort_t)r;
}
__device__ __forceinline__ float bf2f(ushort_t x) {
    return __uint_as_float(((unsigned)x) << 16);
}

// ---------------- CSR+CSC build ----------------
__global__ void count2_k(const int* __restrict__ src, const int* __restrict__ dst,
                         int* __restrict__ cnts, int* __restrict__ cntd) {
    int e = blockIdx.x * 256 + threadIdx.x;
    if (e >= Ee) return;
    atomicAdd(&cnts[src[e]], 1);
    atomicAdd(&cntd[dst[e]], 1);
}

__global__ void scan_local_k(const int* __restrict__ counts, int* __restrict__ rowp,
                             int* __restrict__ bsums) {
    __shared__ int sh[256];
    int t = threadIdx.x;
    int idx = blockIdx.x * 256 + t;
    int v = (idx < Nn) ? counts[idx] : 0;
    sh[t] = v;
    __syncthreads();
    for (int o = 1; o < 256; o <<= 1) {
        int x = (t >= o) ? sh[t - o] : 0;
        __syncthreads();
        sh[t] += x;
        __syncthreads();
    }
    if (idx < Nn) rowp[idx] = sh[t] - v;   // exclusive within block
    if (t == 255) bsums[blockIdx.x] = sh[t];
}

__global__ void scan_tot_k(int* __restrict__ bsums, int nb) {
    __shared__ int sh[512];
    int t = threadIdx.x;
    int v = (t < nb) ? bsums[t] : 0;
    sh[t] = v;
    __syncthreads();
    for (int o = 1; o < 512; o <<= 1) {
        int x = (t >= o) ? sh[t - o] : 0;
        __syncthreads();
        sh[t] += x;
        __syncthreads();
    }
    if (t < nb) bsums[t] = sh[t] - v;      // exclusive block offsets
}

__global__ void scan_add_k(int* __restrict__ rowp, const int* __restrict__ bsums,
                           int* __restrict__ cursor) {
    int idx = blockIdx.x * 256 + threadIdx.x;
    if (idx < Nn) {
        int r = rowp[idx] + bsums[blockIdx.x];
        rowp[idx] = r;
        cursor[idx] = r;
    }
    if (blockIdx.x == 0 && threadIdx.x == 0) rowp[Nn] = Ee;
}

__global__ void fill2_k(const int* __restrict__ src, const int* __restrict__ dst,
                        int* __restrict__ curs, int* __restrict__ curd,
                        int* __restrict__ csr_dst, int* __restrict__ csc_src) {
    int e = blockIdx.x * 256 + threadIdx.x;
    if (e >= Ee) return;
    int s = src[e], d = dst[e];
    int ps = atomicAdd(&curs[s], 1);
    csr_dst[ps] = d;
    int pd = atomicAdd(&curd[d], 1);
    csc_src[pd] = s;
}

// ---------------- GEMM: C[N,64/head] = X[N,256] @ W + b; optional bf16-out, fused a1/a2, ELU, add ----------------
template <int BF16OUT, int FUSEA, int ELU, int ADD>
__global__ __launch_bounds__(256) void gemm_k(const float* __restrict__ X,
                                              const float* __restrict__ W, int whstride,
                                              const float* __restrict__ bias, int bhstride,
                                              const float* __restrict__ addp,
                                              ushort_t* __restrict__ outb,
                                              float* __restrict__ outf, int orstride,
                                              const float* __restrict__ wl,
                                              const float* __restrict__ wr,
                                              const float* __restrict__ bl,
                                              const float* __restrict__ br,
                                              float* __restrict__ a1,
                                              float* __restrict__ a2, int astride) {
    __shared__ float As[64][65];
    __shared__ float Ws[64][64];
    int tid = threadIdx.x;
    int head = blockIdx.y;
    const float* Wp = W + (size_t)head * whstride;
    const float* bp = bias + (size_t)head * bhstride;
    int m0 = blockIdx.x * 64;
    int trow = tid >> 4, tcol = tid & 15;
    float acc[4][4] = {};
    for (int kc = 0; kc < 4; ++kc) {
        int k0 = kc * 64;
#pragma unroll
        for (int t = 0; t < 4; ++t) {
            int f4 = tid + t * 256;
            int row = f4 >> 4, c4 = f4 & 15;
            int r = m0 + row;
            float4 av = (r < Nn) ? *(const float4*)(X + (size_t)r * 256 + k0 + c4 * 4)
                                 : make_float4(0.f, 0.f, 0.f, 0.f);
            As[row][c4 * 4 + 0] = av.x;
            As[row][c4 * 4 + 1] = av.y;
            As[row][c4 * 4 + 2] = av.z;
            As[row][c4 * 4 + 3] = av.w;
            float4 wv = *(const float4*)(Wp + (size_t)(k0 + row) * 64 + c4 * 4);
            *(float4*)&Ws[row][c4 * 4] = wv;
        }
        __syncthreads();
#pragma unroll 8
        for (int k = 0; k < 64; ++k) {
            float a0 = As[trow * 4 + 0][k];
            float a1v = As[trow * 4 + 1][k];
            float a2v = As[trow * 4 + 2][k];
            float a3 = As[trow * 4 + 3][k];
            float4 w = *(float4*)&Ws[k][tcol * 4];
            acc[0][0] += a0 * w.x;  acc[0][1] += a0 * w.y;  acc[0][2] += a0 * w.z;  acc[0][3] += a0 * w.w;
            acc[1][0] += a1v * w.x; acc[1][1] += a1v * w.y; acc[1][2] += a1v * w.z; acc[1][3] += a1v * w.w;
            acc[2][0] += a2v * w.x; acc[2][1] += a2v * w.y; acc[2][2] += a2v * w.z; acc[2][3] += a2v * w.w;
            acc[3][0] += a3 * w.x;  acc[3][1] += a3 * w.y;  acc[3][2] += a3 * w.z;  acc[3][3] += a3 * w.w;
        }
        __syncthreads();
    }
    float4 b4 = *(const float4*)(bp + tcol * 4);
    float4 wl4, wr4;
    if (FUSEA) {
        wl4 = *(const float4*)(wl + head * 64 + tcol * 4);
        wr4 = *(const float4*)(wr + head * 64 + tcol * 4);
    }
#pragma unroll
    for (int i = 0; i < 4; ++i) {
        int r = m0 + trow * 4 + i;
        float v0 = acc[i][0] + b4.x;
        float v1 = acc[i][1] + b4.y;
        float v2 = acc[i][2] + b4.z;
        float v3 = acc[i][3] + b4.w;
        if (ADD && r < Nn) {
            float4 ad = *(const float4*)(addp + (size_t)r * 64 + tcol * 4);
            v0 += ad.x; v1 += ad.y; v2 += ad.z; v3 += ad.w;
        }
        if (FUSEA) {
            float p1 = v0 * wl4.x + v1 * wl4.y + v2 * wl4.z + v3 * wl4.w;
            float p2 = v0 * wr4.x + v1 * wr4.y + v2 * wr4.z + v3 * wr4.w;
#pragma unroll
            for (int o = 1; o < 16; o <<= 1) {
                p1 += __shfl_xor(p1, o);
                p2 += __shfl_xor(p2, o);
            }
            if (tcol == 0 && r < Nn) {
                a1[(size_t)r * astride + head] = p1 + bl[head];
                a2[(size_t)r * astride + head] = p2 + br[head];
            }
        }
        if (ELU) {
            v0 = v0 > 0.f ? v0 : __expf(v0) - 1.f;
            v1 = v1 > 0.f ? v1 : __expf(v1) - 1.f;
            v2 = v2 > 0.f ? v2 : __expf(v2) - 1.f;
            v3 = v3 > 0.f ? v3 : __expf(v3) - 1.f;
        }
        if (r < Nn) {
            if (BF16OUT) {
                ushort4 o4;
                o4.x = f2bf(v0); o4.y = f2bf(v1); o4.z = f2bf(v2); o4.w = f2bf(v3);
                *(ushort4*)(outb + (size_t)r * orstride + head * 64 + tcol * 4) = o4;
            } else {
                *(float4*)(outf + (size_t)r * orstride + head * 64 + tcol * 4) =
                    make_float4(v0, v1, v2, v3);
            }
        }
    }
}

// ---------------- max pass (CSC walk): m[d] = max(0, max_e leaky(a1[d]+a2[src])) ----------------
__global__ __launch_bounds__(256) void maxpass4_k(const int* __restrict__ rowpd,
                                                  const int* __restrict__ cscsrc,
                                                  const float* __restrict__ a1,
                                                  const float* __restrict__ a2,
                                                  float* __restrict__ mmax) {
    int node = blockIdx.x * 4 + (threadIdx.x >> 6);
    int lane = threadIdx.x & 63;
    if (node >= Nn) return;
    int h = lane & 3, ei = lane >> 2;
    int r0 = rowpd[node], r1 = rowpd[node + 1];
    float a1v = a1[node * 4 + h];
    float m = 0.f;
    for (int i = r0 + ei; i < r1; i += 16) {
        int s = cscsrc[i];
        float v = a1v + a2[s * 4 + h];
        float a = v > 0.f ? v : 0.01f * v;
        m = fmaxf(m, a);
    }
#pragma unroll
    for (int o = 4; o < 64; o <<= 1) m = fmaxf(m, __shfl_xor(m, o));
    if (lane < 4) mmax[node * 4 + lane] = m;
}

__global__ __launch_bounds__(256) void maxpass1_k(const int* __restrict__ rowpd,
                                                  const int* __restrict__ cscsrc,
                                                  const float* __restrict__ a1,
                                                  const float* __restrict__ a2,
                                                  float* __restrict__ mmax) {
    int node = blockIdx.x * 4 + (threadIdx.x >> 6);
    int lane = threadIdx.x & 63;
    if (node >= Nn) return;
    int r0 = rowpd[node], r1 = rowpd[node + 1];
    float a1v = a1[node];
    float m = 0.f;
    for (int i = r0 + lane; i < r1; i += 64) {
        float v = a1v + a2[cscsrc[i]];
        float a = v > 0.f ? v : 0.01f * v;
        m = fmaxf(m, a);
    }
#pragma unroll
    for (int o = 1; o < 64; o <<= 1) m = fmaxf(m, __shfl_xor(m, o));
    if (lane == 0) mmax[node] = m;
}

// ---------------- sum pass (CSR walk): ea[i]=exp(a-m[dst]); S[s]=sum ----------------
__global__ __launch_bounds__(256) void sumpass4_k(const int* __restrict__ rowps,
                                                  const int* __restrict__ csrdst,
                                                  const float* __restrict__ a1,
                                                  const float* __restrict__ a2,
                                                  const float* __restrict__ mmax,
                                                  float* __restrict__ eacsr,
                                                  float* __restrict__ Ssum) {
    int node = blockIdx.x * 4 + (threadIdx.x >> 6);
    int lane = threadIdx.x & 63;
    if (node >= Nn) return;
    int h = lane & 3, ei = lane >> 2;
    int r0 = rowps[node], r1 = rowps[node + 1];
    float a2v = a2[node * 4 + h];
    float S = 0.f;
    for (int i = r0 + ei; i < r1; i += 16) {
        int d = csrdst[i];
        float v = a1[d * 4 + h] + a2v;
        float a = v > 0.f ? v : 0.01f * v;
        float ea = __expf(a - mmax[d * 4 + h]);
        eacsr[(size_t)i * 4 + h] = ea;
        S += ea;
    }
#pragma unroll
    for (int o = 4; o < 64; o <<= 1) S += __shfl_xor(S, o);
    if (lane < 4) Ssum[node * 4 + lane] = S;
}

__global__ __launch_bounds__(256) void sumpass1_k(const int* __restrict__ rowps,
                                                  const int* __restrict__ csrdst,
                                                  const float* __restrict__ a1,
                                                  const float* __restrict__ a2,
                                                  const float* __restrict__ mmax,
                                                  float* __restrict__ eacsr,
                                                  float* __restrict__ Ssum) {
    int node = blockIdx.x * 4 + (threadIdx.x >> 6);
    int lane = threadIdx.x & 63;
    if (node >= Nn) return;
    int r0 = rowps[node], r1 = rowps[node + 1];
    float a2v = a2[node];
    float S = 0.f;
    for (int i = r0 + lane; i < r1; i += 64) {
        int d = csrdst[i];
        float v = a1[d] + a2v;
        float a = v > 0.f ? v : 0.01f * v;
        float ea = __expf(a - mmax[d]);
        eacsr[i] = ea;
        S += ea;
    }
#pragma unroll
    for (int o = 1; o < 64; o <<= 1) S += __shfl_xor(S, o);
    if (lane == 0) Ssum[node] = S;
}

// ---------------- edge pass C (layer 1, 4 heads): last[src] = elu(sum (ea/S[dst]) * ftb[dst]) ----------------
__global__ __launch_bounds__(256) void edgeC4_k(const int* __restrict__ rowp,
                                                const int* __restrict__ cdst,
                                                const float* __restrict__ eacsr,
                                                const float* __restrict__ S4,
                                                const ushort_t* __restrict__ ftb,
                                                float* __restrict__ lastp) {
    int node = blockIdx.x * 4 + (threadIdx.x >> 6);
    int lane = threadIdx.x & 63;
    if (node >= Nn) return;
    int h = lane >> 4;  // head = lane/16; channels (lane&15)*4 within head
    int r0 = rowp[node], r1 = rowp[node + 1];
    float ax = 0.f, ay = 0.f, az = 0.f, aw = 0.f;
    for (int i = r0; i < r1; ++i) {
        int d = cdst[i];
        float w = __fdividef(eacsr[(size_t)i * 4 + h], S4[d * 4 + h]);
        ushort4 f = *(const ushort4*)(ftb + (size_t)d * 256 + lane * 4);
        ax += w * bf2f(f.x);
        ay += w * bf2f(f.y);
        az += w * bf2f(f.z);
        aw += w * bf2f(f.w);
    }
    ax = ax > 0.f ? ax : __expf(ax) - 1.f;
    ay = ay > 0.f ? ay : __expf(ay) - 1.f;
    az = az > 0.f ? az : __expf(az) - 1.f;
    aw = aw > 0.f ? aw : __expf(aw) - 1.f;
    *(float4*)(lastp + (size_t)node * 256 + lane * 4) = make_float4(ax, ay, az, aw);
}

// ---------------- edge pass C (layer 2): out2[src] = sum (ea/S[dst]) * ftb2[dst] ----------------
// half-wave per edge: lanes 0-31 handle even edge, 32-63 odd edge; each lane 2 channels
__global__ __launch_bounds__(256) void edgeC1_k(const int* __restrict__ rowp,
                                                const int* __restrict__ cdst,
                                                const float* __restrict__ ea,
                                                const float* __restrict__ S2,
                                                const ushort_t* __restrict__ ftb2,
                                                float* __restrict__ outp) {
    int node = blockIdx.x * 4 + (threadIdx.x >> 6);
    int lane = threadIdx.x & 63;
    if (node >= Nn) return;
    int half = lane >> 5, l = lane & 31;
    int r0 = rowp[node], r1 = rowp[node + 1];
    float acc0 = 0.f, acc1 = 0.f;
    for (int i0 = r0; i0 < r1; i0 += 2) {
        int i = i0 + half;
        if (i < r1) {
            int d = cdst[i];
            float w = __fdividef(ea[i], S2[d]);
            ushort2 f = *(const ushort2*)(ftb2 + (size_t)d * 64 + l * 2);
            acc0 += w * bf2f(f.x);
            acc1 += w * bf2f(f.y);
        }
    }
    acc0 += __shfl_xor(acc0, 32);
    acc1 += __shfl_xor(acc1, 32);
    if (lane < 32) {
        *(float2*)(outp + (size_t)node * 64 + l * 2) = make_float2(acc0, acc1);
    }
}

// ---------------- launch ----------------
extern "C" void kernel_launch(void* const* d_in, const int* in_sizes, int n_in,
                              void* d_out, int out_size, void* d_ws, size_t ws_size,
                              hipStream_t stream) {
    const float* features = (const float*)d_in[0];
    const int* src = (const int*)d_in[1];
    const int* dst = (const int*)d_in[2];
    const float* W_fc = (const float*)d_in[3];
    const float* b_fc = (const float*)d_in[4];
    const float* w_al = (const float*)d_in[5];
    const float* b_al = (const float*)d_in[6];
    const float* w_ar = (const float*)d_in[7];
    const float* b_ar = (const float*)d_in[8];
    const float* W_res = (const float*)d_in[9];
    const float* b_res = (const float*)d_in[10];
    float* out = (float*)d_out;
    char* ws = (char*)d_ws;

    int* rowps = (int*)(ws + O_ROWPS);
    int* rowpd = (int*)(ws + O_ROWPD);
    int* cnts = (int*)(ws + O_CNTS);
    int* cntd = (int*)(ws + O_CNTD);
    int* curs = (int*)(ws + O_CURS);
    int* curd = (int*)(ws + O_CURD);
    int* bsums = (int*)(ws + O_BSUMS);
    int* csr_dst = (int*)(ws + O_CSRDST);
    int* csc_src = (int*)(ws + O_CSCSRC);
    ushort_t* ftb1 = (ushort_t*)(ws + O_FTB1);
    ushort_t* ftb2 = (ushort_t*)(ws + O_FTB2);
    float* last = (float*)(ws + O_LAST);
    float* eacsr = (float*)(ws + O_EACSR);
    float* m4 = (float*)(ws + O_M4);
    float* S4 = (float*)(ws + O_S4);
    float* a1_4 = (float*)(ws + O_A14);
    float* a2_4 = (float*)(ws + O_A24);
    float* m2 = (float*)(ws + O_M2);
    float* S2 = (float*)(ws + O_S2);
    float* a1_2 = (float*)(ws + O_A12);
    float* a2_2 = (float*)(ws + O_A22);
    float* out2 = (float*)(ws + O_OUT2);
    float* ea_l2 = (float*)(ws + O_EAL2);

    // zero cnts+cntd in one shot (contiguous)
    hipMemsetAsync(cnts, 0, (size_t)Nn * 8 + 512, stream);

    constexpr int NB = (Nn + 255) / 256;  // 391
    constexpr int EB = (Ee + 255) / 256;
    count2_k<<<EB, 256, 0, stream>>>(src, dst, cnts, cntd);
    scan_local_k<<<NB, 256, 0, stream>>>(cnts, rowps, bsums);
    scan_tot_k<<<1, 512, 0, stream>>>(bsums, NB);
    scan_add_k<<<NB, 256, 0, stream>>>(rowps, bsums, curs);
    scan_local_k<<<NB, 256, 0, stream>>>(cntd, rowpd, bsums);
    scan_tot_k<<<1, 512, 0, stream>>>(bsums, NB);
    scan_add_k<<<NB, 256, 0, stream>>>(rowpd, bsums, curd);
    fill2_k<<<EB, 256, 0, stream>>>(src, dst, curs, curd, csr_dst, csc_src);

    const int MB = (Nn + 63) / 64;  // 1563
    const int NW = (Nn + 3) / 4;    // 25000
    // ---- layer 1: 4 heads (GEMM -> bf16 ft + fused a1/a2) ----
    gemm_k<1, 1, 0, 0><<<dim3(MB, 4), 256, 0, stream>>>(
        features, W_fc, 256 * 64, b_fc, 64, nullptr,
        ftb1, nullptr, 256, w_al, w_ar, b_al, b_ar, a1_4, a2_4, 4);
    maxpass4_k<<<NW, 256, 0, stream>>>(rowpd, csc_src, a1_4, a2_4, m4);
    sumpass4_k<<<NW, 256, 0, stream>>>(rowps, csr_dst, a1_4, a2_4, m4, eacsr, S4);
    edgeC4_k<<<NW, 256, 0, stream>>>(rowps, csr_dst, eacsr, S4, ftb1, last);

    // ---- layer 2: head 4 ----
    gemm_k<1, 1, 0, 0><<<dim3(MB, 1), 256, 0, stream>>>(
        last, W_fc + 4 * 256 * 64, 0, b_fc + 4 * 64, 0, nullptr,
        ftb2, nullptr, 64, w_al + 4 * 64, w_ar + 4 * 64, b_al + 4, b_ar + 4,
        a1_2, a2_2, 1);
    maxpass1_k<<<NW, 256, 0, stream>>>(rowpd, csc_src, a1_2, a2_2, m2);
    sumpass1_k<<<NW, 256, 0, stream>>>(rowps, csr_dst, a1_2, a2_2, m2, ea_l2, S2);
    edgeC1_k<<<NW, 256, 0, stream>>>(rowps, csr_dst, ea_l2, S2, ftb2, out2);

    // ---- final: elu(last @ W_res + b_res + out2) ----
    gemm_k<0, 0, 1, 1><<<dim3(MB, 1), 256, 0, stream>>>(
        last, W_res, 0, b_res, 0, out2,
        nullptr, out, 64, nullptr, nullptr, nullptr, nullptr, nullptr, nullptr, 0);
}

// Round 5
// 794.105 us; speedup vs baseline: 1.9705x; 1.4288x over previous
//
#include <hip/hip_runtime.h>

typedef unsigned short ushort_t;

// ---------------- problem constants ----------------
constexpr int Nn = 100000;   // nodes
constexpr int Ee = 1600000;  // edges
// IN = 256, H = 64, NH = 4 (layer1 heads), head 4 = output head

constexpr int NBUCK = 391;   // ceil(Nn/256) node buckets of 256
constexpr int BCAP  = 6144;  // per-bucket capacity (mean 4096, sigma ~64)
constexpr int CH3   = 8192;  // edges per block in bin pass
constexpr int NBLK3 = (Ee + CH3 - 1) / CH3;  // 196

// ---------------- workspace layout (bytes) ----------------
constexpr size_t O_ROWPS  = 0;              // (Nn+1) int
constexpr size_t O_ROWPD  = 400512;         // (Nn+1) int
constexpr size_t O_BOFF   = 801024;         // 2*392 int
constexpr size_t O_GCUR   = 805120;         // 2*391 int
constexpr size_t O_CSRDST = 809216;         // Ee int
constexpr size_t O_CSCSRC = 7209216;        // Ee int
constexpr size_t O_FTB1   = 13609216;       // Nn*256 bf16 (51.2MB)
constexpr size_t O_FTB2   = 64809216;       // Nn*64 bf16
constexpr size_t O_LAST   = 77609216;       // Nn*256 f32
constexpr size_t O_EACSR  = 180009216;      // Ee*4 f32 (layer1) / Ee f32 (layer2)
constexpr size_t O_M4     = 205609216;      // Nn*4 f32
constexpr size_t O_S4     = 207209216;      // Nn*4 f32
constexpr size_t O_A14    = 208809216;      // Nn*4 f32
constexpr size_t O_A24    = 210409216;      // Nn*4 f32
constexpr size_t O_M2     = 212009216;      // Nn f32
constexpr size_t O_S2     = 212409728;      // Nn f32
constexpr size_t O_A12    = 212810240;      // Nn f32
constexpr size_t O_A22    = 213210752;      // Nn f32
constexpr size_t O_OUT2   = 213611264;      // Nn*64 f32 (end ~239.2MB)
// aliases (lifetimes disjoint):
constexpr size_t O_BUFS   = O_FTB1;                       // 391*6144*8 = 19.2MB
constexpr size_t O_BUFD   = O_FTB1 + (size_t)NBUCK * BCAP * 8;  // +19.2MB (fits in FTB1's 51.2MB)
constexpr size_t O_EAL2   = O_EACSR;

__device__ __forceinline__ ushort_t f2bf(float x) {
    unsigned u = __float_as_uint(x);
    unsigned r = (u + 0x7FFFu + ((u >> 16) & 1u)) >> 16;
    return (ushort_t)r;
}
__device__ __forceinline__ float bf2f(ushort_t x) {
    return __uint_as_float(((unsigned)x) << 16);
}

// ---------------- P3: bin edges into node-range buckets (both orderings) ----------------
__global__ __launch_bounds__(256) void p3_bin_k(const int* __restrict__ src,
                                                const int* __restrict__ dst,
                                                int* __restrict__ gcur,
                                                int2* __restrict__ bufs,
                                                int2* __restrict__ bufd) {
    __shared__ int hs[NBUCK], hd[NBUCK], rs[NBUCK], rd[NBUCK];
    int t = threadIdx.x;
    for (int i = t; i < NBUCK; i += 256) { hs[i] = 0; hd[i] = 0; }
    __syncthreads();
    int e0 = blockIdx.x * CH3;
    int ne = min(CH3, Ee - e0);
    // pass A: per-block histogram
    for (int i = t; i < ne; i += 256) {
        atomicAdd(&hs[src[e0 + i] >> 8], 1);
        atomicAdd(&hd[dst[e0 + i] >> 8], 1);
    }
    __syncthreads();
    // reserve contiguous runs per bucket
    for (int i = t; i < NBUCK; i += 256) {
        rs[i] = hs[i] ? atomicAdd(&gcur[i], hs[i]) : 0;
        rd[i] = hd[i] ? atomicAdd(&gcur[NBUCK + i], hd[i]) : 0;
        hs[i] = 0; hd[i] = 0;
    }
    __syncthreads();
    // pass B: append (key,val) pairs
    for (int i = t; i < ne; i += 256) {
        int s = src[e0 + i], d = dst[e0 + i];
        int bu = s >> 8;
        int pos = rs[bu] + atomicAdd(&hs[bu], 1);
        if (pos < BCAP) bufs[(size_t)bu * BCAP + pos] = make_int2(s, d);
        bu = d >> 8;
        pos = rd[bu] + atomicAdd(&hd[bu], 1);
        if (pos < BCAP) bufd[(size_t)bu * BCAP + pos] = make_int2(d, s);
    }
}

// ---------------- P2: scan bucket counts -> bucket bases (= global CSR offsets) ----------------
__global__ void p2_scan_k(const int* __restrict__ gcur, int* __restrict__ boff,
                          int* __restrict__ rowps, int* __restrict__ rowpd) {
    __shared__ int sh[512];
    int t = threadIdx.x;
    const int* cnt = gcur + blockIdx.x * NBUCK;
    int* bo = boff + blockIdx.x * 392;
    int v = (t < NBUCK) ? min(cnt[t], BCAP) : 0;
    sh[t] = v;
    __syncthreads();
    for (int o = 1; o < 512; o <<= 1) {
        int x = (t >= o) ? sh[t - o] : 0;
        __syncthreads();
        sh[t] += x;
        __syncthreads();
    }
    if (t < NBUCK) bo[t] = sh[t] - v;
    if (t == NBUCK - 1) {
        bo[NBUCK] = sh[t];
        int* rp = blockIdx.x ? rowpd : rowps;
        rp[Nn] = sh[t];
    }
}

// ---------------- P4: per-bucket fill: rowp + sorted value array ----------------
__global__ __launch_bounds__(256) void p4_fill_k(const int* __restrict__ gcur,
                                                 const int* __restrict__ boff,
                                                 const int2* __restrict__ bufs,
                                                 const int2* __restrict__ bufd,
                                                 int* __restrict__ rowps,
                                                 int* __restrict__ rowpd,
                                                 int* __restrict__ csr_dst,
                                                 int* __restrict__ csc_src) {
    __shared__ int cnt[256], lofs[256], sc[256];
    int b = blockIdx.x, st = blockIdx.y;
    const int2* buf = (st ? bufd : bufs) + (size_t)b * BCAP;
    int base = boff[st * 392 + b];
    int total = min(gcur[st * NBUCK + b], BCAP);
    int* rowp = st ? rowpd : rowps;
    int* outv = st ? csc_src : csr_dst;
    int t = threadIdx.x, node0 = b << 8;
    cnt[t] = 0;
    __syncthreads();
    for (int i = t; i < total; i += 256) atomicAdd(&cnt[buf[i].x - node0], 1);
    __syncthreads();
    int v = cnt[t];
    sc[t] = v;
    __syncthreads();
    for (int o = 1; o < 256; o <<= 1) {
        int x = (t >= o) ? sc[t - o] : 0;
        __syncthreads();
        sc[t] += x;
        __syncthreads();
    }
    lofs[t] = sc[t] - v;
    if (node0 + t < Nn) rowp[node0 + t] = base + lofs[t];
    cnt[t] = 0;
    __syncthreads();
    for (int i = t; i < total; i += 256) {
        int2 p = buf[i];
        int k = p.x - node0;
        int r = atomicAdd(&cnt[k], 1);
        outv[base + lofs[k] + r] = p.y;
    }
}

// ---------------- GEMM: C[N,64/head] = X[N,256] @ W + b; optional bf16-out, fused a1/a2, ELU, add ----------------
template <int BF16OUT, int FUSEA, int ELU, int ADD>
__global__ __launch_bounds__(256) void gemm_k(const float* __restrict__ X,
                                              const float* __restrict__ W, int whstride,
                                              const float* __restrict__ bias, int bhstride,
                                              const float* __restrict__ addp,
                                              ushort_t* __restrict__ outb,
                                              float* __restrict__ outf, int orstride,
                                              const float* __restrict__ wl,
                                              const float* __restrict__ wr,
                                              const float* __restrict__ bl,
                                              const float* __restrict__ br,
                                              float* __restrict__ a1,
                                              float* __restrict__ a2, int astride) {
    __shared__ float As[64][65];
    __shared__ float Ws[64][64];
    int tid = threadIdx.x;
    int head = blockIdx.y;
    const float* Wp = W + (size_t)head * whstride;
    const float* bp = bias + (size_t)head * bhstride;
    int m0 = blockIdx.x * 64;
    int trow = tid >> 4, tcol = tid & 15;
    float acc[4][4] = {};
    for (int kc = 0; kc < 4; ++kc) {
        int k0 = kc * 64;
#pragma unroll
        for (int t = 0; t < 4; ++t) {
            int f4 = tid + t * 256;
            int row = f4 >> 4, c4 = f4 & 15;
            int r = m0 + row;
            float4 av = (r < Nn) ? *(const float4*)(X + (size_t)r * 256 + k0 + c4 * 4)
                                 : make_float4(0.f, 0.f, 0.f, 0.f);
            As[row][c4 * 4 + 0] = av.x;
            As[row][c4 * 4 + 1] = av.y;
            As[row][c4 * 4 + 2] = av.z;
            As[row][c4 * 4 + 3] = av.w;
            float4 wv = *(const float4*)(Wp + (size_t)(k0 + row) * 64 + c4 * 4);
            *(float4*)&Ws[row][c4 * 4] = wv;
        }
        __syncthreads();
#pragma unroll 8
        for (int k = 0; k < 64; ++k) {
            float a0 = As[trow * 4 + 0][k];
            float a1v = As[trow * 4 + 1][k];
            float a2v = As[trow * 4 + 2][k];
            float a3 = As[trow * 4 + 3][k];
            float4 w = *(float4*)&Ws[k][tcol * 4];
            acc[0][0] += a0 * w.x;  acc[0][1] += a0 * w.y;  acc[0][2] += a0 * w.z;  acc[0][3] += a0 * w.w;
            acc[1][0] += a1v * w.x; acc[1][1] += a1v * w.y; acc[1][2] += a1v * w.z; acc[1][3] += a1v * w.w;
            acc[2][0] += a2v * w.x; acc[2][1] += a2v * w.y; acc[2][2] += a2v * w.z; acc[2][3] += a2v * w.w;
            acc[3][0] += a3 * w.x;  acc[3][1] += a3 * w.y;  acc[3][2] += a3 * w.z;  acc[3][3] += a3 * w.w;
        }
        __syncthreads();
    }
    float4 b4 = *(const float4*)(bp + tcol * 4);
    float4 wl4, wr4;
    if (FUSEA) {
        wl4 = *(const float4*)(wl + head * 64 + tcol * 4);
        wr4 = *(const float4*)(wr + head * 64 + tcol * 4);
    }
#pragma unroll
    for (int i = 0; i < 4; ++i) {
        int r = m0 + trow * 4 + i;
        float v0 = acc[i][0] + b4.x;
        float v1 = acc[i][1] + b4.y;
        float v2 = acc[i][2] + b4.z;
        float v3 = acc[i][3] + b4.w;
        if (ADD && r < Nn) {
            float4 ad = *(const float4*)(addp + (size_t)r * 64 + tcol * 4);
            v0 += ad.x; v1 += ad.y; v2 += ad.z; v3 += ad.w;
        }
        if (FUSEA) {
            float p1 = v0 * wl4.x + v1 * wl4.y + v2 * wl4.z + v3 * wl4.w;
            float p2 = v0 * wr4.x + v1 * wr4.y + v2 * wr4.z + v3 * wr4.w;
#pragma unroll
            for (int o = 1; o < 16; o <<= 1) {
                p1 += __shfl_xor(p1, o);
                p2 += __shfl_xor(p2, o);
            }
            if (tcol == 0 && r < Nn) {
                a1[(size_t)r * astride + head] = p1 + bl[head];
                a2[(size_t)r * astride + head] = p2 + br[head];
            }
        }
        if (ELU) {
            v0 = v0 > 0.f ? v0 : __expf(v0) - 1.f;
            v1 = v1 > 0.f ? v1 : __expf(v1) - 1.f;
            v2 = v2 > 0.f ? v2 : __expf(v2) - 1.f;
            v3 = v3 > 0.f ? v3 : __expf(v3) - 1.f;
        }
        if (r < Nn) {
            if (BF16OUT) {
                ushort4 o4;
                o4.x = f2bf(v0); o4.y = f2bf(v1); o4.z = f2bf(v2); o4.w = f2bf(v3);
                *(ushort4*)(outb + (size_t)r * orstride + head * 64 + tcol * 4) = o4;
            } else {
                *(float4*)(outf + (size_t)r * orstride + head * 64 + tcol * 4) =
                    make_float4(v0, v1, v2, v3);
            }
        }
    }
}

// ---------------- max pass (CSC walk) ----------------
__global__ __launch_bounds__(256) void maxpass4_k(const int* __restrict__ rowpd,
                                                  const int* __restrict__ cscsrc,
                                                  const float* __restrict__ a1,
                                                  const float* __restrict__ a2,
                                                  float* __restrict__ mmax) {
    int node = blockIdx.x * 4 + (threadIdx.x >> 6);
    int lane = threadIdx.x & 63;
    if (node >= Nn) return;
    int h = lane & 3, ei = lane >> 2;
    int r0 = rowpd[node], r1 = rowpd[node + 1];
    float a1v = a1[node * 4 + h];
    float m = 0.f;
    for (int i = r0 + ei; i < r1; i += 16) {
        int s = cscsrc[i];
        float v = a1v + a2[s * 4 + h];
        float a = v > 0.f ? v : 0.01f * v;
        m = fmaxf(m, a);
    }
#pragma unroll
    for (int o = 4; o < 64; o <<= 1) m = fmaxf(m, __shfl_xor(m, o));
    if (lane < 4) mmax[node * 4 + lane] = m;
}

__global__ __launch_bounds__(256) void maxpass1_k(const int* __restrict__ rowpd,
                                                  const int* __restrict__ cscsrc,
                                                  const float* __restrict__ a1,
                                                  const float* __restrict__ a2,
                                                  float* __restrict__ mmax) {
    int node = blockIdx.x * 4 + (threadIdx.x >> 6);
    int lane = threadIdx.x & 63;
    if (node >= Nn) return;
    int r0 = rowpd[node], r1 = rowpd[node + 1];
    float a1v = a1[node];
    float m = 0.f;
    for (int i = r0 + lane; i < r1; i += 64) {
        float v = a1v + a2[cscsrc[i]];
        float a = v > 0.f ? v : 0.01f * v;
        m = fmaxf(m, a);
    }
#pragma unroll
    for (int o = 1; o < 64; o <<= 1) m = fmaxf(m, __shfl_xor(m, o));
    if (lane == 0) mmax[node] = m;
}

// ---------------- sum pass (CSR walk) ----------------
__global__ __launch_bounds__(256) void sumpass4_k(const int* __restrict__ rowps,
                                                  const int* __restrict__ csrdst,
                                                  const float* __restrict__ a1,
                                                  const float* __restrict__ a2,
                                                  const float* __restrict__ mmax,
                                                  float* __restrict__ eacsr,
                                                  float* __restrict__ Ssum) {
    int node = blockIdx.x * 4 + (threadIdx.x >> 6);
    int lane = threadIdx.x & 63;
    if (node >= Nn) return;
    int h = lane & 3, ei = lane >> 2;
    int r0 = rowps[node], r1 = rowps[node + 1];
    float a2v = a2[node * 4 + h];
    float S = 0.f;
    for (int i = r0 + ei; i < r1; i += 16) {
        int d = csrdst[i];
        float v = a1[d * 4 + h] + a2v;
        float a = v > 0.f ? v : 0.01f * v;
        float ea = __expf(a - mmax[d * 4 + h]);
        eacsr[(size_t)i * 4 + h] = ea;
        S += ea;
    }
#pragma unroll
    for (int o = 4; o < 64; o <<= 1) S += __shfl_xor(S, o);
    if (lane < 4) Ssum[node * 4 + lane] = S;
}

__global__ __launch_bounds__(256) void sumpass1_k(const int* __restrict__ rowps,
                                                  const int* __restrict__ csrdst,
                                                  const float* __restrict__ a1,
                                                  const float* __restrict__ a2,
                                                  const float* __restrict__ mmax,
                                                  float* __restrict__ eacsr,
                                                  float* __restrict__ Ssum) {
    int node = blockIdx.x * 4 + (threadIdx.x >> 6);
    int lane = threadIdx.x & 63;
    if (node >= Nn) return;
    int r0 = rowps[node], r1 = rowps[node + 1];
    float a2v = a2[node];
    float S = 0.f;
    for (int i = r0 + lane; i < r1; i += 64) {
        int d = csrdst[i];
        float v = a1[d] + a2v;
        float a = v > 0.f ? v : 0.01f * v;
        float ea = __expf(a - mmax[d]);
        eacsr[i] = ea;
        S += ea;
    }
#pragma unroll
    for (int o = 1; o < 64; o <<= 1) S += __shfl_xor(S, o);
    if (lane == 0) Ssum[node] = S;
}

// ---------------- edge pass C (layer 1, 4 heads) ----------------
__global__ __launch_bounds__(256) void edgeC4_k(const int* __restrict__ rowp,
                                                const int* __restrict__ cdst,
                                                const float* __restrict__ eacsr,
                                                const float* __restrict__ S4,
                                                const ushort_t* __restrict__ ftb,
                                                float* __restrict__ lastp) {
    int node = blockIdx.x * 4 + (threadIdx.x >> 6);
    int lane = threadIdx.x & 63;
    if (node >= Nn) return;
    int h = lane >> 4;
    int r0 = rowp[node], r1 = rowp[node + 1];
    float ax = 0.f, ay = 0.f, az = 0.f, aw = 0.f;
    for (int i = r0; i < r1; ++i) {
        int d = cdst[i];
        float w = __fdividef(eacsr[(size_t)i * 4 + h], S4[d * 4 + h]);
        ushort4 f = *(const ushort4*)(ftb + (size_t)d * 256 + lane * 4);
        ax += w * bf2f(f.x);
        ay += w * bf2f(f.y);
        az += w * bf2f(f.z);
        aw += w * bf2f(f.w);
    }
    ax = ax > 0.f ? ax : __expf(ax) - 1.f;
    ay = ay > 0.f ? ay : __expf(ay) - 1.f;
    az = az > 0.f ? az : __expf(az) - 1.f;
    aw = aw > 0.f ? aw : __expf(aw) - 1.f;
    *(float4*)(lastp + (size_t)node * 256 + lane * 4) = make_float4(ax, ay, az, aw);
}

// ---------------- edge pass C (layer 2) ----------------
__global__ __launch_bounds__(256) void edgeC1_k(const int* __restrict__ rowp,
                                                const int* __restrict__ cdst,
                                                const float* __restrict__ ea,
                                                const float* __restrict__ S2,
                                                const ushort_t* __restrict__ ftb2,
                                                float* __restrict__ outp) {
    int node = blockIdx.x * 4 + (threadIdx.x >> 6);
    int lane = threadIdx.x & 63;
    if (node >= Nn) return;
    int half = lane >> 5, l = lane & 31;
    int r0 = rowp[node], r1 = rowp[node + 1];
    float acc0 = 0.f, acc1 = 0.f;
    for (int i0 = r0; i0 < r1; i0 += 2) {
        int i = i0 + half;
        if (i < r1) {
            int d = cdst[i];
            float w = __fdividef(ea[i], S2[d]);
            ushort2 f = *(const ushort2*)(ftb2 + (size_t)d * 64 + l * 2);
            acc0 += w * bf2f(f.x);
            acc1 += w * bf2f(f.y);
        }
    }
    acc0 += __shfl_xor(acc0, 32);
    acc1 += __shfl_xor(acc1, 32);
    if (lane < 32) {
        *(float2*)(outp + (size_t)node * 64 + l * 2) = make_float2(acc0, acc1);
    }
}

// ---------------- launch ----------------
extern "C" void kernel_launch(void* const* d_in, const int* in_sizes, int n_in,
                              void* d_out, int out_size, void* d_ws, size_t ws_size,
                              hipStream_t stream) {
    const float* features = (const float*)d_in[0];
    const int* src = (const int*)d_in[1];
    const int* dst = (const int*)d_in[2];
    const float* W_fc = (const float*)d_in[3];
    const float* b_fc = (const float*)d_in[4];
    const float* w_al = (const float*)d_in[5];
    const float* b_al = (const float*)d_in[6];
    const float* w_ar = (const float*)d_in[7];
    const float* b_ar = (const float*)d_in[8];
    const float* W_res = (const float*)d_in[9];
    const float* b_res = (const float*)d_in[10];
    float* out = (float*)d_out;
    char* ws = (char*)d_ws;

    int* rowps = (int*)(ws + O_ROWPS);
    int* rowpd = (int*)(ws + O_ROWPD);
    int* boff = (int*)(ws + O_BOFF);
    int* gcur = (int*)(ws + O_GCUR);
    int* csr_dst = (int*)(ws + O_CSRDST);
    int* csc_src = (int*)(ws + O_CSCSRC);
    int2* bufs = (int2*)(ws + O_BUFS);
    int2* bufd = (int2*)(ws + O_BUFD);
    ushort_t* ftb1 = (ushort_t*)(ws + O_FTB1);
    ushort_t* ftb2 = (ushort_t*)(ws + O_FTB2);
    float* last = (float*)(ws + O_LAST);
    float* eacsr = (float*)(ws + O_EACSR);
    float* m4 = (float*)(ws + O_M4);
    float* S4 = (float*)(ws + O_S4);
    float* a1_4 = (float*)(ws + O_A14);
    float* a2_4 = (float*)(ws + O_A24);
    float* m2 = (float*)(ws + O_M2);
    float* S2 = (float*)(ws + O_S2);
    float* a1_2 = (float*)(ws + O_A12);
    float* a2_2 = (float*)(ws + O_A22);
    float* out2 = (float*)(ws + O_OUT2);
    float* ea_l2 = (float*)(ws + O_EAL2);

    // ---- graph build: bucketed counting sort (CSR by src + CSC by dst) ----
    hipMemsetAsync(gcur, 0, 2 * NBUCK * 4, stream);
    p3_bin_k<<<NBLK3, 256, 0, stream>>>(src, dst, gcur, bufs, bufd);
    p2_scan_k<<<2, 512, 0, stream>>>(gcur, boff, rowps, rowpd);
    p4_fill_k<<<dim3(NBUCK, 2), 256, 0, stream>>>(gcur, boff, bufs, bufd,
                                                  rowps, rowpd, csr_dst, csc_src);

    const int MB = (Nn + 63) / 64;  // 1563
    const int NW = (Nn + 3) / 4;    // 25000
    // ---- layer 1: 4 heads (GEMM -> bf16 ft + fused a1/a2) ----
    gemm_k<1, 1, 0, 0><<<dim3(MB, 4), 256, 0, stream>>>(
        features, W_fc, 256 * 64, b_fc, 64, nullptr,
        ftb1, nullptr, 256, w_al, w_ar, b_al, b_ar, a1_4, a2_4, 4);
    maxpass4_k<<<NW, 256, 0, stream>>>(rowpd, csc_src, a1_4, a2_4, m4);
    sumpass4_k<<<NW, 256, 0, stream>>>(rowps, csr_dst, a1_4, a2_4, m4, eacsr, S4);
    edgeC4_k<<<NW, 256, 0, stream>>>(rowps, csr_dst, eacsr, S4, ftb1, last);

    // ---- layer 2: head 4 ----
    gemm_k<1, 1, 0, 0><<<dim3(MB, 1), 256, 0, stream>>>(
        last, W_fc + 4 * 256 * 64, 0, b_fc + 4 * 64, 0, nullptr,
        ftb2, nullptr, 64, w_al + 4 * 64, w_ar + 4 * 64, b_al + 4, b_ar + 4,
        a1_2, a2_2, 1);
    maxpass1_k<<<NW, 256, 0, stream>>>(rowpd, csc_src, a1_2, a2_2, m2);
    sumpass1_k<<<NW, 256, 0, stream>>>(rowps, csr_dst, a1_2, a2_2, m2, ea_l2, S2);
    edgeC1_k<<<NW, 256, 0, stream>>>(rowps, csr_dst, ea_l2, S2, ftb2, out2);

    // ---- final: elu(last @ W_res + b_res + out2) ----
    gemm_k<0, 0, 1, 1><<<dim3(MB, 1), 256, 0, stream>>>(
        last, W_res, 0, b_res, 0, out2,
        nullptr, out, 64, nullptr, nullptr, nullptr, nullptr, nullptr, nullptr, 0);
}

// Round 7
// 573.259 us; speedup vs baseline: 2.7296x; 1.3852x over previous
//
#include <hip/hip_runtime.h>

typedef unsigned short ushort_t;
typedef __attribute__((ext_vector_type(8))) short bf16x8;
typedef __attribute__((ext_vector_type(4))) float f32x4;

// ---------------- problem constants ----------------
constexpr int Nn = 100000;   // nodes
constexpr int Ee = 1600000;  // edges
// IN = 256, H = 64, NH = 4 (layer1 heads), head 4 = output head

constexpr int NBUCK = 391;   // ceil(Nn/256) node buckets of 256
constexpr int BCAP  = 6144;  // per-bucket capacity (mean 4096, sigma ~64)
constexpr int CH3   = 8192;  // edges per block in bin pass
constexpr int NBLK3 = (Ee + CH3 - 1) / CH3;  // 196

// ---------------- workspace layout (bytes) ----------------
constexpr size_t O_ROWPS  = 0;              // (Nn+1) int
constexpr size_t O_ROWPD  = 400512;         // (Nn+1) int
constexpr size_t O_BOFF   = 801024;         // 2*392 int
constexpr size_t O_GCUR   = 805120;         // 2*391 int
constexpr size_t O_CSRDST = 809216;         // Ee int
constexpr size_t O_CSCSRC = 7209216;        // Ee int
constexpr size_t O_FTB1   = 13609216;       // Nn*256 bf16 (51.2MB)
constexpr size_t O_FTB2   = 64809216;       // Nn*64 bf16
constexpr size_t O_LASTB  = 77609216;       // Nn*256 bf16 (51.2MB)
constexpr size_t O_EACSR  = 180009216;      // Ee*4 f32 (layer1) / Ee f32 (layer2)
constexpr size_t O_M4     = 205609216;      // Nn*4 f32
constexpr size_t O_S4     = 207209216;      // Nn*4 f32
constexpr size_t O_A14    = 208809216;      // Nn*4 f32
constexpr size_t O_A24    = 210409216;      // Nn*4 f32
constexpr size_t O_M2     = 212009216;      // Nn f32
constexpr size_t O_S2     = 212409728;      // Nn f32
constexpr size_t O_A12    = 212810240;      // Nn f32
constexpr size_t O_A22    = 213210752;      // Nn f32
constexpr size_t O_OUT2   = 213611264;      // Nn*64 f32
constexpr size_t O_WT1    = 239211264;      // 256*256 bf16 (layer1 weights, [col][k])
constexpr size_t O_WT2    = 239342336;      // 64*256 bf16
constexpr size_t O_WTR    = 239375104;      // 64*256 bf16   end ~239.4MB
// aliases (lifetimes disjoint):
constexpr size_t O_BUFS   = O_FTB1;
constexpr size_t O_BUFD   = O_FTB1 + (size_t)NBUCK * BCAP * 8;
constexpr size_t O_EAL2   = O_EACSR;

__device__ __forceinline__ ushort_t f2bf(float x) {
    unsigned u = __float_as_uint(x);
    unsigned r = (u + 0x7FFFu + ((u >> 16) & 1u)) >> 16;
    return (ushort_t)r;
}
__device__ __forceinline__ float bf2f(ushort_t x) {
    return __uint_as_float(((unsigned)x) << 16);
}

// ---------------- weight pre-transpose+convert: Wt[col][k] bf16 ----------------
__global__ void wcvt_k(const float* __restrict__ Wfc, const float* __restrict__ Wres,
                       ushort_t* __restrict__ Wt1, ushort_t* __restrict__ Wt2,
                       ushort_t* __restrict__ WtR) {
    int g = blockIdx.x * 256 + threadIdx.x;
    if (g < 65536) {
        int c = g >> 8, k = g & 255;
        Wt1[g] = f2bf(Wfc[(size_t)(c >> 6) * 16384 + k * 64 + (c & 63)]);
    } else if (g < 81920) {
        int q = g - 65536;
        int c = q >> 8, k = q & 255;
        Wt2[q] = f2bf(Wfc[4 * 16384 + k * 64 + c]);
    } else {
        int q = g - 81920;
        int c = q >> 8, k = q & 255;
        WtR[q] = f2bf(Wres[k * 64 + c]);
    }
}

// ---------------- P3: bin edges into node-range buckets (both orderings) ----------------
__global__ __launch_bounds__(256) void p3_bin_k(const int* __restrict__ src,
                                                const int* __restrict__ dst,
                                                int* __restrict__ gcur,
                                                int2* __restrict__ bufs,
                                                int2* __restrict__ bufd) {
    __shared__ int hs[NBUCK], hd[NBUCK], rs[NBUCK], rd[NBUCK];
    int t = threadIdx.x;
    for (int i = t; i < NBUCK; i += 256) { hs[i] = 0; hd[i] = 0; }
    __syncthreads();
    int e0 = blockIdx.x * CH3;
    int ne = min(CH3, Ee - e0);
    for (int i = t; i < ne; i += 256) {
        atomicAdd(&hs[src[e0 + i] >> 8], 1);
        atomicAdd(&hd[dst[e0 + i] >> 8], 1);
    }
    __syncthreads();
    for (int i = t; i < NBUCK; i += 256) {
        rs[i] = hs[i] ? atomicAdd(&gcur[i], hs[i]) : 0;
        rd[i] = hd[i] ? atomicAdd(&gcur[NBUCK + i], hd[i]) : 0;
        hs[i] = 0; hd[i] = 0;
    }
    __syncthreads();
    for (int i = t; i < ne; i += 256) {
        int s = src[e0 + i], d = dst[e0 + i];
        int bu = s >> 8;
        int pos = rs[bu] + atomicAdd(&hs[bu], 1);
        if (pos < BCAP) bufs[(size_t)bu * BCAP + pos] = make_int2(s, d);
        bu = d >> 8;
        pos = rd[bu] + atomicAdd(&hd[bu], 1);
        if (pos < BCAP) bufd[(size_t)bu * BCAP + pos] = make_int2(d, s);
    }
}

// ---------------- P2: scan bucket counts ----------------
__global__ void p2_scan_k(const int* __restrict__ gcur, int* __restrict__ boff,
                          int* __restrict__ rowps, int* __restrict__ rowpd) {
    __shared__ int sh[512];
    int t = threadIdx.x;
    const int* cnt = gcur + blockIdx.x * NBUCK;
    int* bo = boff + blockIdx.x * 392;
    int v = (t < NBUCK) ? min(cnt[t], BCAP) : 0;
    sh[t] = v;
    __syncthreads();
    for (int o = 1; o < 512; o <<= 1) {
        int x = (t >= o) ? sh[t - o] : 0;
        __syncthreads();
        sh[t] += x;
        __syncthreads();
    }
    if (t < NBUCK) bo[t] = sh[t] - v;
    if (t == NBUCK - 1) {
        bo[NBUCK] = sh[t];
        int* rp = blockIdx.x ? rowpd : rowps;
        rp[Nn] = sh[t];
    }
}

// ---------------- P4: per-bucket fill ----------------
__global__ __launch_bounds__(256) void p4_fill_k(const int* __restrict__ gcur,
                                                 const int* __restrict__ boff,
                                                 const int2* __restrict__ bufs,
                                                 const int2* __restrict__ bufd,
                                                 int* __restrict__ rowps,
                                                 int* __restrict__ rowpd,
                                                 int* __restrict__ csr_dst,
                                                 int* __restrict__ csc_src) {
    __shared__ int cnt[256], lofs[256], sc[256];
    int b = blockIdx.x, st = blockIdx.y;
    const int2* buf = (st ? bufd : bufs) + (size_t)b * BCAP;
    int base = boff[st * 392 + b];
    int total = min(gcur[st * NBUCK + b], BCAP);
    int* rowp = st ? rowpd : rowps;
    int* outv = st ? csc_src : csr_dst;
    int t = threadIdx.x, node0 = b << 8;
    cnt[t] = 0;
    __syncthreads();
    for (int i = t; i < total; i += 256) atomicAdd(&cnt[buf[i].x - node0], 1);
    __syncthreads();
    int v = cnt[t];
    sc[t] = v;
    __syncthreads();
    for (int o = 1; o < 256; o <<= 1) {
        int x = (t >= o) ? sc[t - o] : 0;
        __syncthreads();
        sc[t] += x;
        __syncthreads();
    }
    lofs[t] = sc[t] - v;
    if (node0 + t < Nn) rowp[node0 + t] = base + lofs[t];
    cnt[t] = 0;
    __syncthreads();
    for (int i = t; i < total; i += 256) {
        int2 p = buf[i];
        int k = p.x - node0;
        int r = atomicAdd(&cnt[k], 1);
        outv[base + lofs[k] + r] = p.y;
    }
}

// ---------------- MFMA GEMM: C[N,BN] = A[N,256] @ Bt^T + bias (+add) ----------------
// A: f32 (ABF16=0) or bf16 (ABF16=1); Bt: bf16 [ncols][256]; 128-row block tile,
// 4 waves as WGM x (4/WGM); per-wave tile (128/WGM) x 64; 16x16x32 bf16 MFMA.
template <int ABF16, int BN, int WGM, int FUSEA, int ADD, int ELU, int BF16OUT>
__global__ __launch_bounds__(256) void mgemm_k(
    const float* __restrict__ Af, const ushort_t* __restrict__ Ab,
    const ushort_t* __restrict__ Bt, const float* __restrict__ bias,
    const float* __restrict__ addp,
    ushort_t* __restrict__ outb, float* __restrict__ outf, int ostride,
    const float* __restrict__ wl, const float* __restrict__ wr,
    const float* __restrict__ blp, const float* __restrict__ brp,
    float* __restrict__ a1, float* __restrict__ a2, int astride) {
    constexpr int MROWS = 128 / WGM;
    constexpr int MREP = MROWS / 16;
    constexpr int LDA = 40;  // shorts per LDS row (32 + 8 pad -> 2-way conflicts only)
    __shared__ short As[128 * LDA];
    __shared__ short Bs[BN * LDA];
    int tid = threadIdx.x;
    int m0 = blockIdx.x * 128;
    int col0 = blockIdx.y * BN;
    int w = tid >> 6, l = tid & 63;
    int wr_ = w % WGM, wc = w / WGM;
    int lr = l & 15, lg = l >> 4;
    f32x4 acc[MREP][4];
#pragma unroll
    for (int m = 0; m < MREP; ++m)
#pragma unroll
        for (int n = 0; n < 4; ++n) acc[m][n] = (f32x4){0.f, 0.f, 0.f, 0.f};

    for (int kc = 0; kc < 8; ++kc) {
        int k0 = kc * 32;
        if (ABF16 == 0) {
            // f32 A: thread -> (row, half of 16 floats); convert to bf16
            int r = tid >> 1, half = tid & 1;
            int grow = m0 + r;
            float4 f0, f1, f2, f3;
            if (grow < Nn) {
                const float4* ap = (const float4*)(Af + (size_t)grow * 256 + k0 + half * 16);
                f0 = ap[0]; f1 = ap[1]; f2 = ap[2]; f3 = ap[3];
            } else {
                f0 = f1 = f2 = f3 = make_float4(0.f, 0.f, 0.f, 0.f);
            }
            bf16x8 s0, s1;
            s0[0] = f2bf(f0.x); s0[1] = f2bf(f0.y); s0[2] = f2bf(f0.z); s0[3] = f2bf(f0.w);
            s0[4] = f2bf(f1.x); s0[5] = f2bf(f1.y); s0[6] = f2bf(f1.z); s0[7] = f2bf(f1.w);
            s1[0] = f2bf(f2.x); s1[1] = f2bf(f2.y); s1[2] = f2bf(f2.z); s1[3] = f2bf(f2.w);
            s1[4] = f2bf(f3.x); s1[5] = f2bf(f3.y); s1[6] = f2bf(f3.z); s1[7] = f2bf(f3.w);
            *(bf16x8*)&As[r * LDA + half * 16] = s0;
            *(bf16x8*)&As[r * LDA + half * 16 + 8] = s1;
        } else {
            // bf16 A: 512 slots of 8 bf16
#pragma unroll
            for (int i = 0; i < 2; ++i) {
                int s = tid + i * 256, r = s >> 2, q = s & 3;
                int grow = m0 + r;
                int4 v = make_int4(0, 0, 0, 0);
                if (grow < Nn) v = *(const int4*)(Ab + (size_t)grow * 256 + k0 + q * 8);
                *(int4*)&As[r * LDA + q * 8] = v;
            }
        }
        // B stage: BN rows of 32 bf16
#pragma unroll
        for (int i = 0; i < BN / 64; ++i) {
            int s = tid + i * 256, c = s >> 2, q = s & 3;
            int4 v = *(const int4*)(Bt + (size_t)(col0 + c) * 256 + k0 + q * 8);
            *(int4*)&Bs[c * LDA + q * 8] = v;
        }
        __syncthreads();
        bf16x8 af[MREP], bfr[4];
#pragma unroll
        for (int m = 0; m < MREP; ++m)
            af[m] = *(const bf16x8*)&As[(wr_ * MROWS + m * 16 + lr) * LDA + lg * 8];
#pragma unroll
        for (int n = 0; n < 4; ++n)
            bfr[n] = *(const bf16x8*)&Bs[(wc * 64 + n * 16 + lr) * LDA + lg * 8];
#pragma unroll
        for (int m = 0; m < MREP; ++m)
#pragma unroll
            for (int n = 0; n < 4; ++n)
                acc[m][n] = __builtin_amdgcn_mfma_f32_16x16x32_bf16(af[m], bfr[n], acc[m][n], 0, 0, 0);
        __syncthreads();
    }

    // epilogue: D[row][col]: col = coln[n], row = base + lg*4 + e  (m89 layout)
    int coln[4];
    float biasv[4], wlv[4] = {}, wrv[4] = {};
    #pragma unroll
    for (int n = 0; n < 4; ++n) {
        coln[n] = col0 + wc * 64 + n * 16 + lr;
        biasv[n] = bias[coln[n]];
        if (FUSEA) { wlv[n] = wl[coln[n]]; wrv[n] = wr[coln[n]]; }
    }
    int head = (col0 + wc * 64) >> 6;
#pragma unroll
    for (int m = 0; m < MREP; ++m) {
#pragma unroll
        for (int e = 0; e < 4; ++e) {
            int row = m0 + wr_ * MROWS + m * 16 + lg * 4 + e;
            bool ok = row < Nn;
            float vv[4], p1 = 0.f, p2 = 0.f;
#pragma unroll
            for (int n = 0; n < 4; ++n) {
                float v = acc[m][n][e] + biasv[n];
                if (ADD) v += ok ? addp[(size_t)row * 64 + coln[n]] : 0.f;
                if (FUSEA) { p1 += v * wlv[n]; p2 += v * wrv[n]; }
                if (ELU) v = v > 0.f ? v : __expf(v) - 1.f;
                vv[n] = v;
            }
            if (FUSEA) {
#pragma unroll
                for (int o = 1; o < 16; o <<= 1) {
                    p1 += __shfl_xor(p1, o);
                    p2 += __shfl_xor(p2, o);
                }
                if (lr == 0 && ok) {
                    a1[(size_t)row * astride + head] = p1 + blp[head];
                    a2[(size_t)row * astride + head] = p2 + brp[head];
                }
            }
            if (ok) {
#pragma unroll
                for (int n = 0; n < 4; ++n) {
                    if (BF16OUT)
                        outb[(size_t)row * ostride + coln[n]] = f2bf(vv[n]);
                    else
                        outf[(size_t)row * ostride + coln[n]] = vv[n];
                }
            }
        }
    }
}

// ---------------- max pass (CSC walk) ----------------
__global__ __launch_bounds__(256) void maxpass4_k(const int* __restrict__ rowpd,
                                                  const int* __restrict__ cscsrc,
                                                  const float* __restrict__ a1,
                                                  const float* __restrict__ a2,
                                                  float* __restrict__ mmax) {
    int node = blockIdx.x * 4 + (threadIdx.x >> 6);
    int lane = threadIdx.x & 63;
    if (node >= Nn) return;
    int h = lane & 3, ei = lane >> 2;
    int r0 = rowpd[node], r1 = rowpd[node + 1];
    float a1v = a1[node * 4 + h];
    float m = 0.f;
    for (int i = r0 + ei; i < r1; i += 16) {
        int s = cscsrc[i];
        float v = a1v + a2[s * 4 + h];
        float a = v > 0.f ? v : 0.01f * v;
        m = fmaxf(m, a);
    }
#pragma unroll
    for (int o = 4; o < 64; o <<= 1) m = fmaxf(m, __shfl_xor(m, o));
    if (lane < 4) mmax[node * 4 + lane] = m;
}

__global__ __launch_bounds__(256) void maxpass1_k(const int* __restrict__ rowpd,
                                                  const int* __restrict__ cscsrc,
                                                  const float* __restrict__ a1,
                                                  const float* __restrict__ a2,
                                                  float* __restrict__ mmax) {
    int node = blockIdx.x * 4 + (threadIdx.x >> 6);
    int lane = threadIdx.x & 63;
    if (node >= Nn) return;
    int r0 = rowpd[node], r1 = rowpd[node + 1];
    float a1v = a1[node];
    float m = 0.f;
    for (int i = r0 + lane; i < r1; i += 64) {
        float v = a1v + a2[cscsrc[i]];
        float a = v > 0.f ? v : 0.01f * v;
        m = fmaxf(m, a);
    }
#pragma unroll
    for (int o = 1; o < 64; o <<= 1) m = fmaxf(m, __shfl_xor(m, o));
    if (lane == 0) mmax[node] = m;
}

// ---------------- sum pass (CSR walk) ----------------
__global__ __launch_bounds__(256) void sumpass4_k(const int* __restrict__ rowps,
                                                  const int* __restrict__ csrdst,
                                                  const float* __restrict__ a1,
                                                  const float* __restrict__ a2,
                                                  const float* __restrict__ mmax,
                                                  float* __restrict__ eacsr,
                                                  float* __restrict__ Ssum) {
    int node = blockIdx.x * 4 + (threadIdx.x >> 6);
    int lane = threadIdx.x & 63;
    if (node >= Nn) return;
    int h = lane & 3, ei = lane >> 2;
    int r0 = rowps[node], r1 = rowps[node + 1];
    float a2v = a2[node * 4 + h];
    float S = 0.f;
    for (int i = r0 + ei; i < r1; i += 16) {
        int d = csrdst[i];
        float v = a1[d * 4 + h] + a2v;
        float a = v > 0.f ? v : 0.01f * v;
        float ea = __expf(a - mmax[d * 4 + h]);
        eacsr[(size_t)i * 4 + h] = ea;
        S += ea;
    }
#pragma unroll
    for (int o = 4; o < 64; o <<= 1) S += __shfl_xor(S, o);
    if (lane < 4) Ssum[node * 4 + lane] = S;
}

__global__ __launch_bounds__(256) void sumpass1_k(const int* __restrict__ rowps,
                                                  const int* __restrict__ csrdst,
                                                  const float* __restrict__ a1,
                                                  const float* __restrict__ a2,
                                                  const float* __restrict__ mmax,
                                                  float* __restrict__ eacsr,
                                                  float* __restrict__ Ssum) {
    int node = blockIdx.x * 4 + (threadIdx.x >> 6);
    int lane = threadIdx.x & 63;
    if (node >= Nn) return;
    int r0 = rowps[node], r1 = rowps[node + 1];
    float a2v = a2[node];
    float S = 0.f;
    for (int i = r0 + lane; i < r1; i += 64) {
        int d = csrdst[i];
        float v = a1[d] + a2v;
        float a = v > 0.f ? v : 0.01f * v;
        float ea = __expf(a - mmax[d]);
        eacsr[i] = ea;
        S += ea;
    }
#pragma unroll
    for (int o = 1; o < 64; o <<= 1) S += __shfl_xor(S, o);
    if (lane == 0) Ssum[node] = S;
}

// ---------------- edge pass C (layer 1, 4 heads): lastb = bf16(elu(agg)) ----------------
__global__ __launch_bounds__(256) void edgeC4_k(const int* __restrict__ rowp,
                                                const int* __restrict__ cdst,
                                                const float* __restrict__ eacsr,
                                                const float* __restrict__ S4,
                                                const ushort_t* __restrict__ ftb,
                                                ushort_t* __restrict__ lastb) {
    int node = blockIdx.x * 4 + (threadIdx.x >> 6);
    int lane = threadIdx.x & 63;
    if (node >= Nn) return;
    int h = lane >> 4;
    int r0 = rowp[node], r1 = rowp[node + 1];
    float ax = 0.f, ay = 0.f, az = 0.f, aw = 0.f;
    for (int i = r0; i < r1; ++i) {
        int d = cdst[i];
        float w = __fdividef(eacsr[(size_t)i * 4 + h], S4[d * 4 + h]);
        ushort4 f = *(const ushort4*)(ftb + (size_t)d * 256 + lane * 4);
        ax += w * bf2f(f.x);
        ay += w * bf2f(f.y);
        az += w * bf2f(f.z);
        aw += w * bf2f(f.w);
    }
    ax = ax > 0.f ? ax : __expf(ax) - 1.f;
    ay = ay > 0.f ? ay : __expf(ay) - 1.f;
    az = az > 0.f ? az : __expf(az) - 1.f;
    aw = aw > 0.f ? aw : __expf(aw) - 1.f;
    ushort4 o4;
    o4.x = f2bf(ax); o4.y = f2bf(ay); o4.z = f2bf(az); o4.w = f2bf(aw);
    *(ushort4*)(lastb + (size_t)node * 256 + lane * 4) = o4;
}

// ---------------- edge pass C (layer 2) ----------------
__global__ __launch_bounds__(256) void edgeC1_k(const int* __restrict__ rowp,
                                                const int* __restrict__ cdst,
                                                const float* __restrict__ ea,
                                                const float* __restrict__ S2,
                                                const ushort_t* __restrict__ ftb2,
                                                float* __restrict__ outp) {
    int node = blockIdx.x * 4 + (threadIdx.x >> 6);
    int lane = threadIdx.x & 63;
    if (node >= Nn) return;
    int half = lane >> 5, l = lane & 31;
    int r0 = rowp[node], r1 = rowp[node + 1];
    float acc0 = 0.f, acc1 = 0.f;
    for (int i0 = r0; i0 < r1; i0 += 2) {
        int i = i0 + half;
        if (i < r1) {
            int d = cdst[i];
            float w = __fdividef(ea[i], S2[d]);
            ushort2 f = *(const ushort2*)(ftb2 + (size_t)d * 64 + l * 2);
            acc0 += w * bf2f(f.x);
            acc1 += w * bf2f(f.y);
        }
    }
    acc0 += __shfl_xor(acc0, 32);
    acc1 += __shfl_xor(acc1, 32);
    if (lane < 32) {
        *(float2*)(outp + (size_t)node * 64 + l * 2) = make_float2(acc0, acc1);
    }
}

// ---------------- launch ----------------
extern "C" void kernel_launch(void* const* d_in, const int* in_sizes, int n_in,
                              void* d_out, int out_size, void* d_ws, size_t ws_size,
                              hipStream_t stream) {
    const float* features = (const float*)d_in[0];
    const int* src = (const int*)d_in[1];
    const int* dst = (const int*)d_in[2];
    const float* W_fc = (const float*)d_in[3];
    const float* b_fc = (const float*)d_in[4];
    const float* w_al = (const float*)d_in[5];
    const float* b_al = (const float*)d_in[6];
    const float* w_ar = (const float*)d_in[7];
    const float* b_ar = (const float*)d_in[8];
    const float* W_res = (const float*)d_in[9];
    const float* b_res = (const float*)d_in[10];
    float* out = (float*)d_out;
    char* ws = (char*)d_ws;

    int* rowps = (int*)(ws + O_ROWPS);
    int* rowpd = (int*)(ws + O_ROWPD);
    int* boff = (int*)(ws + O_BOFF);
    int* gcur = (int*)(ws + O_GCUR);
    int* csr_dst = (int*)(ws + O_CSRDST);
    int* csc_src = (int*)(ws + O_CSCSRC);
    int2* bufs = (int2*)(ws + O_BUFS);
    int2* bufd = (int2*)(ws + O_BUFD);
    ushort_t* ftb1 = (ushort_t*)(ws + O_FTB1);
    ushort_t* ftb2 = (ushort_t*)(ws + O_FTB2);
    ushort_t* lastb = (ushort_t*)(ws + O_LASTB);
    float* eacsr = (float*)(ws + O_EACSR);
    float* m4 = (float*)(ws + O_M4);
    float* S4 = (float*)(ws + O_S4);
    float* a1_4 = (float*)(ws + O_A14);
    float* a2_4 = (float*)(ws + O_A24);
    float* m2 = (float*)(ws + O_M2);
    float* S2 = (float*)(ws + O_S2);
    float* a1_2 = (float*)(ws + O_A12);
    float* a2_2 = (float*)(ws + O_A22);
    float* out2 = (float*)(ws + O_OUT2);
    float* ea_l2 = (float*)(ws + O_EAL2);
    ushort_t* Wt1 = (ushort_t*)(ws + O_WT1);
    ushort_t* Wt2 = (ushort_t*)(ws + O_WT2);
    ushort_t* WtR = (ushort_t*)(ws + O_WTR);

    // ---- weight convert/transpose (tiny) ----
    wcvt_k<<<384, 256, 0, stream>>>(W_fc, W_res, Wt1, Wt2, WtR);

    // ---- graph build: bucketed counting sort ----
    hipMemsetAsync(gcur, 0, 2 * NBUCK * 4, stream);
    p3_bin_k<<<NBLK3, 256, 0, stream>>>(src, dst, gcur, bufs, bufd);
    p2_scan_k<<<2, 512, 0, stream>>>(gcur, boff, rowps, rowpd);
    p4_fill_k<<<dim3(NBUCK, 2), 256, 0, stream>>>(gcur, boff, bufs, bufd,
                                                  rowps, rowpd, csr_dst, csc_src);

    const int GB = (Nn + 127) / 128;  // 782
    const int NW = (Nn + 3) / 4;      // 25000
    // ---- layer 1: single MFMA GEMM over all 4 heads (N=256, 2 column panels) ----
    mgemm_k<0, 128, 2, 1, 0, 0, 1><<<dim3(GB, 2), 256, 0, stream>>>(
        features, nullptr, Wt1, b_fc, nullptr,
        ftb1, nullptr, 256, w_al, w_ar, b_al, b_ar, a1_4, a2_4, 4);
    maxpass4_k<<<NW, 256, 0, stream>>>(rowpd, csc_src, a1_4, a2_4, m4);
    sumpass4_k<<<NW, 256, 0, stream>>>(rowps, csr_dst, a1_4, a2_4, m4, eacsr, S4);
    edgeC4_k<<<NW, 256, 0, stream>>>(rowps, csr_dst, eacsr, S4, ftb1, lastb);

    // ---- layer 2: head 4 (A = lastb bf16) ----
    mgemm_k<1, 64, 4, 1, 0, 0, 1><<<dim3(GB, 1), 256, 0, stream>>>(
        nullptr, lastb, Wt2, b_fc + 256, nullptr,
        ftb2, nullptr, 64, w_al + 256, w_ar + 256, b_al + 4, b_ar + 4,
        a1_2, a2_2, 1);
    maxpass1_k<<<NW, 256, 0, stream>>>(rowpd, csc_src, a1_2, a2_2, m2);
    sumpass1_k<<<NW, 256, 0, stream>>>(rowps, csr_dst, a1_2, a2_2, m2, ea_l2, S2);
    edgeC1_k<<<NW, 256, 0, stream>>>(rowps, csr_dst, ea_l2, S2, ftb2, out2);

    // ---- final: elu(lastb @ WtR^T + b_res + out2) -> f32 out ----
    mgemm_k<1, 64, 4, 0, 1, 1, 0><<<dim3(GB, 1), 256, 0, stream>>>(
        nullptr, lastb, WtR, b_res, out2,
        nullptr, out, 64, nullptr, nullptr, nullptr, nullptr, nullptr, nullptr, 0);
}

// Round 8
// 491.450 us; speedup vs baseline: 3.1840x; 1.1665x over previous
//
#include <hip/hip_runtime.h>

typedef unsigned short ushort_t;
typedef __attribute__((ext_vector_type(8))) short bf16x8;
typedef __attribute__((ext_vector_type(4))) float f32x4;

// ---------------- problem constants ----------------
constexpr int Nn = 100000;   // nodes
constexpr int Ee = 1600000;  // edges
// IN = 256, H = 64, NH = 4 (layer1 heads), head 4 = output head

constexpr int NBUCK = 391;   // ceil(Nn/256) node buckets of 256
constexpr int BCAP  = 6144;  // per-bucket capacity (mean 4096, sigma ~64)
constexpr int CH3   = 8192;  // edges per block in bin pass
constexpr int NBLK3 = (Ee + CH3 - 1) / CH3;  // 196

// ---------------- workspace layout (bytes) ----------------
constexpr size_t O_ROWPS  = 0;              // (Nn+1) int
constexpr size_t O_ROWPD  = 400512;         // (Nn+1) int
constexpr size_t O_BOFF   = 801024;         // 2*392 int
constexpr size_t O_GCUR   = 805120;         // 2*391 int
constexpr size_t O_CSRDST = 809216;         // Ee int
constexpr size_t O_CSCSRC = 7209216;        // Ee int
constexpr size_t O_FTB1   = 13609216;       // Nn*256 bf16 (51.2MB)
constexpr size_t O_FTB2   = 64809216;       // Nn*64 bf16
constexpr size_t O_LASTB  = 77609216;       // Nn*256 bf16 (51.2MB)
constexpr size_t O_EACSR  = 180009216;      // Ee*4 f32 (layer1) / Ee f32 (layer2)
constexpr size_t O_M4     = 205609216;      // Nn*4 f32
constexpr size_t O_S4     = 207209216;      // Nn*4 f32
constexpr size_t O_A14    = 208809216;      // Nn*4 f32
constexpr size_t O_A24    = 210409216;      // Nn*4 f32
constexpr size_t O_M2     = 212009216;      // Nn f32
constexpr size_t O_S2     = 212409728;      // Nn f32
constexpr size_t O_A12    = 212810240;      // Nn f32
constexpr size_t O_A22    = 213210752;      // Nn f32
constexpr size_t O_OUT2   = 213611264;      // Nn*64 f32
constexpr size_t O_WT1    = 239211264;      // 256*256 bf16 (layer1 weights, [col][k])
constexpr size_t O_WT2    = 239342336;      // 64*256 bf16
constexpr size_t O_WTR    = 239375104;      // 64*256 bf16   end ~239.4MB
// aliases (lifetimes disjoint):
constexpr size_t O_BUFS   = O_FTB1;
constexpr size_t O_BUFD   = O_FTB1 + (size_t)NBUCK * BCAP * 8;
constexpr size_t O_EAL2   = O_EACSR;

__device__ __forceinline__ ushort_t f2bf(float x) {
    unsigned u = __float_as_uint(x);
    unsigned r = (u + 0x7FFFu + ((u >> 16) & 1u)) >> 16;
    return (ushort_t)r;
}
__device__ __forceinline__ float bf2f(ushort_t x) {
    return __uint_as_float(((unsigned)x) << 16);
}

// ---------------- weight pre-transpose+convert: Wt[col][k] bf16 ----------------
__global__ void wcvt_k(const float* __restrict__ Wfc, const float* __restrict__ Wres,
                       ushort_t* __restrict__ Wt1, ushort_t* __restrict__ Wt2,
                       ushort_t* __restrict__ WtR) {
    int g = blockIdx.x * 256 + threadIdx.x;
    if (g < 65536) {
        int c = g >> 8, k = g & 255;
        Wt1[g] = f2bf(Wfc[(size_t)(c >> 6) * 16384 + k * 64 + (c & 63)]);
    } else if (g < 81920) {
        int q = g - 65536;
        int c = q >> 8, k = q & 255;
        Wt2[q] = f2bf(Wfc[4 * 16384 + k * 64 + c]);
    } else {
        int q = g - 81920;
        int c = q >> 8, k = q & 255;
        WtR[q] = f2bf(Wres[k * 64 + c]);
    }
}

// ---------------- P3: bin edges into node-range buckets (both orderings) ----------------
__global__ __launch_bounds__(256) void p3_bin_k(const int* __restrict__ src,
                                                const int* __restrict__ dst,
                                                int* __restrict__ gcur,
                                                int2* __restrict__ bufs,
                                                int2* __restrict__ bufd) {
    __shared__ int hs[NBUCK], hd[NBUCK], rs[NBUCK], rd[NBUCK];
    int t = threadIdx.x;
    for (int i = t; i < NBUCK; i += 256) { hs[i] = 0; hd[i] = 0; }
    __syncthreads();
    int e0 = blockIdx.x * CH3;
    int ne = min(CH3, Ee - e0);
    for (int i = t; i < ne; i += 256) {
        atomicAdd(&hs[src[e0 + i] >> 8], 1);
        atomicAdd(&hd[dst[e0 + i] >> 8], 1);
    }
    __syncthreads();
    for (int i = t; i < NBUCK; i += 256) {
        rs[i] = hs[i] ? atomicAdd(&gcur[i], hs[i]) : 0;
        rd[i] = hd[i] ? atomicAdd(&gcur[NBUCK + i], hd[i]) : 0;
        hs[i] = 0; hd[i] = 0;
    }
    __syncthreads();
    for (int i = t; i < ne; i += 256) {
        int s = src[e0 + i], d = dst[e0 + i];
        int bu = s >> 8;
        int pos = rs[bu] + atomicAdd(&hs[bu], 1);
        if (pos < BCAP) bufs[(size_t)bu * BCAP + pos] = make_int2(s, d);
        bu = d >> 8;
        pos = rd[bu] + atomicAdd(&hd[bu], 1);
        if (pos < BCAP) bufd[(size_t)bu * BCAP + pos] = make_int2(d, s);
    }
}

// ---------------- P2: scan bucket counts ----------------
__global__ void p2_scan_k(const int* __restrict__ gcur, int* __restrict__ boff,
                          int* __restrict__ rowps, int* __restrict__ rowpd) {
    __shared__ int sh[512];
    int t = threadIdx.x;
    const int* cnt = gcur + blockIdx.x * NBUCK;
    int* bo = boff + blockIdx.x * 392;
    int v = (t < NBUCK) ? min(cnt[t], BCAP) : 0;
    sh[t] = v;
    __syncthreads();
    for (int o = 1; o < 512; o <<= 1) {
        int x = (t >= o) ? sh[t - o] : 0;
        __syncthreads();
        sh[t] += x;
        __syncthreads();
    }
    if (t < NBUCK) bo[t] = sh[t] - v;
    if (t == NBUCK - 1) {
        bo[NBUCK] = sh[t];
        int* rp = blockIdx.x ? rowpd : rowps;
        rp[Nn] = sh[t];
    }
}

// ---------------- P4: per-bucket fill ----------------
__global__ __launch_bounds__(256) void p4_fill_k(const int* __restrict__ gcur,
                                                 const int* __restrict__ boff,
                                                 const int2* __restrict__ bufs,
                                                 const int2* __restrict__ bufd,
                                                 int* __restrict__ rowps,
                                                 int* __restrict__ rowpd,
                                                 int* __restrict__ csr_dst,
                                                 int* __restrict__ csc_src) {
    __shared__ int cnt[256], lofs[256], sc[256];
    int b = blockIdx.x, st = blockIdx.y;
    const int2* buf = (st ? bufd : bufs) + (size_t)b * BCAP;
    int base = boff[st * 392 + b];
    int total = min(gcur[st * NBUCK + b], BCAP);
    int* rowp = st ? rowpd : rowps;
    int* outv = st ? csc_src : csr_dst;
    int t = threadIdx.x, node0 = b << 8;
    cnt[t] = 0;
    __syncthreads();
    for (int i = t; i < total; i += 256) atomicAdd(&cnt[buf[i].x - node0], 1);
    __syncthreads();
    int v = cnt[t];
    sc[t] = v;
    __syncthreads();
    for (int o = 1; o < 256; o <<= 1) {
        int x = (t >= o) ? sc[t - o] : 0;
        __syncthreads();
        sc[t] += x;
        __syncthreads();
    }
    lofs[t] = sc[t] - v;
    if (node0 + t < Nn) rowp[node0 + t] = base + lofs[t];
    cnt[t] = 0;
    __syncthreads();
    for (int i = t; i < total; i += 256) {
        int2 p = buf[i];
        int k = p.x - node0;
        int r = atomicAdd(&cnt[k], 1);
        outv[base + lofs[k] + r] = p.y;
    }
}

// ---------------- MFMA GEMM: C[N,BN] = A[N,256] @ Bt^T + bias (+add) ----------------
template <int ABF16, int BN, int WGM, int FUSEA, int ADD, int ELU, int BF16OUT>
__global__ __launch_bounds__(256) void mgemm_k(
    const float* __restrict__ Af, const ushort_t* __restrict__ Ab,
    const ushort_t* __restrict__ Bt, const float* __restrict__ bias,
    const float* __restrict__ addp,
    ushort_t* __restrict__ outb, float* __restrict__ outf, int ostride,
    const float* __restrict__ wl, const float* __restrict__ wr,
    const float* __restrict__ blp, const float* __restrict__ brp,
    float* __restrict__ a1, float* __restrict__ a2, int astride) {
    constexpr int MROWS = 128 / WGM;
    constexpr int MREP = MROWS / 16;
    constexpr int LDA = 40;  // shorts per LDS row (32 + 8 pad -> 2-way conflicts only)
    __shared__ short As[128 * LDA];
    __shared__ short Bs[BN * LDA];
    int tid = threadIdx.x;
    int m0 = blockIdx.x * 128;
    int col0 = blockIdx.y * BN;
    int w = tid >> 6, l = tid & 63;
    int wr_ = w % WGM, wc = w / WGM;
    int lr = l & 15, lg = l >> 4;
    f32x4 acc[MREP][4];
#pragma unroll
    for (int m = 0; m < MREP; ++m)
#pragma unroll
        for (int n = 0; n < 4; ++n) acc[m][n] = (f32x4){0.f, 0.f, 0.f, 0.f};

    for (int kc = 0; kc < 8; ++kc) {
        int k0 = kc * 32;
        if (ABF16 == 0) {
            int r = tid >> 1, half = tid & 1;
            int grow = m0 + r;
            float4 f0, f1, f2, f3;
            if (grow < Nn) {
                const float4* ap = (const float4*)(Af + (size_t)grow * 256 + k0 + half * 16);
                f0 = ap[0]; f1 = ap[1]; f2 = ap[2]; f3 = ap[3];
            } else {
                f0 = f1 = f2 = f3 = make_float4(0.f, 0.f, 0.f, 0.f);
            }
            bf16x8 s0, s1;
            s0[0] = f2bf(f0.x); s0[1] = f2bf(f0.y); s0[2] = f2bf(f0.z); s0[3] = f2bf(f0.w);
            s0[4] = f2bf(f1.x); s0[5] = f2bf(f1.y); s0[6] = f2bf(f1.z); s0[7] = f2bf(f1.w);
            s1[0] = f2bf(f2.x); s1[1] = f2bf(f2.y); s1[2] = f2bf(f2.z); s1[3] = f2bf(f2.w);
            s1[4] = f2bf(f3.x); s1[5] = f2bf(f3.y); s1[6] = f2bf(f3.z); s1[7] = f2bf(f3.w);
            *(bf16x8*)&As[r * LDA + half * 16] = s0;
            *(bf16x8*)&As[r * LDA + half * 16 + 8] = s1;
        } else {
#pragma unroll
            for (int i = 0; i < 2; ++i) {
                int s = tid + i * 256, r = s >> 2, q = s & 3;
                int grow = m0 + r;
                int4 v = make_int4(0, 0, 0, 0);
                if (grow < Nn) v = *(const int4*)(Ab + (size_t)grow * 256 + k0 + q * 8);
                *(int4*)&As[r * LDA + q * 8] = v;
            }
        }
#pragma unroll
        for (int i = 0; i < BN / 64; ++i) {
            int s = tid + i * 256, c = s >> 2, q = s & 3;
            int4 v = *(const int4*)(Bt + (size_t)(col0 + c) * 256 + k0 + q * 8);
            *(int4*)&Bs[c * LDA + q * 8] = v;
        }
        __syncthreads();
        bf16x8 af[MREP], bfr[4];
#pragma unroll
        for (int m = 0; m < MREP; ++m)
            af[m] = *(const bf16x8*)&As[(wr_ * MROWS + m * 16 + lr) * LDA + lg * 8];
#pragma unroll
        for (int n = 0; n < 4; ++n)
            bfr[n] = *(const bf16x8*)&Bs[(wc * 64 + n * 16 + lr) * LDA + lg * 8];
#pragma unroll
        for (int m = 0; m < MREP; ++m)
#pragma unroll
            for (int n = 0; n < 4; ++n)
                acc[m][n] = __builtin_amdgcn_mfma_f32_16x16x32_bf16(af[m], bfr[n], acc[m][n], 0, 0, 0);
        __syncthreads();
    }

    int coln[4];
    float biasv[4], wlv[4] = {}, wrv[4] = {};
    #pragma unroll
    for (int n = 0; n < 4; ++n) {
        coln[n] = col0 + wc * 64 + n * 16 + lr;
        biasv[n] = bias[coln[n]];
        if (FUSEA) { wlv[n] = wl[coln[n]]; wrv[n] = wr[coln[n]]; }
    }
    int head = (col0 + wc * 64) >> 6;
#pragma unroll
    for (int m = 0; m < MREP; ++m) {
#pragma unroll
        for (int e = 0; e < 4; ++e) {
            int row = m0 + wr_ * MROWS + m * 16 + lg * 4 + e;
            bool ok = row < Nn;
            float vv[4], p1 = 0.f, p2 = 0.f;
#pragma unroll
            for (int n = 0; n < 4; ++n) {
                float v = acc[m][n][e] + biasv[n];
                if (ADD) v += ok ? addp[(size_t)row * 64 + coln[n]] : 0.f;
                if (FUSEA) { p1 += v * wlv[n]; p2 += v * wrv[n]; }
                if (ELU) v = v > 0.f ? v : __expf(v) - 1.f;
                vv[n] = v;
            }
            if (FUSEA) {
#pragma unroll
                for (int o = 1; o < 16; o <<= 1) {
                    p1 += __shfl_xor(p1, o);
                    p2 += __shfl_xor(p2, o);
                }
                if (lr == 0 && ok) {
                    a1[(size_t)row * astride + head] = p1 + blp[head];
                    a2[(size_t)row * astride + head] = p2 + brp[head];
                }
            }
            if (ok) {
#pragma unroll
                for (int n = 0; n < 4; ++n) {
                    if (BF16OUT)
                        outb[(size_t)row * ostride + coln[n]] = f2bf(vv[n]);
                    else
                        outf[(size_t)row * ostride + coln[n]] = vv[n];
                }
            }
        }
    }
}

// ---------------- max pass (CSC walk) ----------------
__global__ __launch_bounds__(256) void maxpass4_k(const int* __restrict__ rowpd,
                                                  const int* __restrict__ cscsrc,
                                                  const float* __restrict__ a1,
                                                  const float* __restrict__ a2,
                                                  float* __restrict__ mmax) {
    int node = blockIdx.x * 4 + (threadIdx.x >> 6);
    int lane = threadIdx.x & 63;
    if (node >= Nn) return;
    int h = lane & 3, ei = lane >> 2;
    int r0 = rowpd[node], r1 = rowpd[node + 1];
    float a1v = a1[node * 4 + h];
    float m = 0.f;
    for (int i = r0 + ei; i < r1; i += 16) {
        int s = cscsrc[i];
        float v = a1v + a2[s * 4 + h];
        float a = v > 0.f ? v : 0.01f * v;
        m = fmaxf(m, a);
    }
#pragma unroll
    for (int o = 4; o < 64; o <<= 1) m = fmaxf(m, __shfl_xor(m, o));
    if (lane < 4) mmax[node * 4 + lane] = m;
}

__global__ __launch_bounds__(256) void maxpass1_k(const int* __restrict__ rowpd,
                                                  const int* __restrict__ cscsrc,
                                                  const float* __restrict__ a1,
                                                  const float* __restrict__ a2,
                                                  float* __restrict__ mmax) {
    int node = blockIdx.x * 4 + (threadIdx.x >> 6);
    int lane = threadIdx.x & 63;
    if (node >= Nn) return;
    int r0 = rowpd[node], r1 = rowpd[node + 1];
    float a1v = a1[node];
    float m = 0.f;
    for (int i = r0 + lane; i < r1; i += 64) {
        float v = a1v + a2[cscsrc[i]];
        float a = v > 0.f ? v : 0.01f * v;
        m = fmaxf(m, a);
    }
#pragma unroll
    for (int o = 1; o < 64; o <<= 1) m = fmaxf(m, __shfl_xor(m, o));
    if (lane == 0) mmax[node] = m;
}

// ---------------- sum pass (CSR walk) ----------------
__global__ __launch_bounds__(256) void sumpass4_k(const int* __restrict__ rowps,
                                                  const int* __restrict__ csrdst,
                                                  const float* __restrict__ a1,
                                                  const float* __restrict__ a2,
                                                  const float* __restrict__ mmax,
                                                  float* __restrict__ eacsr,
                                                  float* __restrict__ Ssum) {
    int node = blockIdx.x * 4 + (threadIdx.x >> 6);
    int lane = threadIdx.x & 63;
    if (node >= Nn) return;
    int h = lane & 3, ei = lane >> 2;
    int r0 = rowps[node], r1 = rowps[node + 1];
    float a2v = a2[node * 4 + h];
    float S = 0.f;
    for (int i = r0 + ei; i < r1; i += 16) {
        int d = csrdst[i];
        float v = a1[d * 4 + h] + a2v;
        float a = v > 0.f ? v : 0.01f * v;
        float ea = __expf(a - mmax[d * 4 + h]);
        eacsr[(size_t)i * 4 + h] = ea;
        S += ea;
    }
#pragma unroll
    for (int o = 4; o < 64; o <<= 1) S += __shfl_xor(S, o);
    if (lane < 4) Ssum[node * 4 + lane] = S;
}

__global__ __launch_bounds__(256) void sumpass1_k(const int* __restrict__ rowps,
                                                  const int* __restrict__ csrdst,
                                                  const float* __restrict__ a1,
                                                  const float* __restrict__ a2,
                                                  const float* __restrict__ mmax,
                                                  float* __restrict__ eacsr,
                                                  float* __restrict__ Ssum) {
    int node = blockIdx.x * 4 + (threadIdx.x >> 6);
    int lane = threadIdx.x & 63;
    if (node >= Nn) return;
    int r0 = rowps[node], r1 = rowps[node + 1];
    float a2v = a2[node];
    float S = 0.f;
    for (int i = r0 + lane; i < r1; i += 64) {
        int d = csrdst[i];
        float v = a1[d] + a2v;
        float a = v > 0.f ? v : 0.01f * v;
        float ea = __expf(a - mmax[d]);
        eacsr[i] = ea;
        S += ea;
    }
#pragma unroll
    for (int o = 1; o < 64; o <<= 1) S += __shfl_xor(S, o);
    if (lane == 0) Ssum[node] = S;
}

// ---------------- edge pass C (layer 1, 4 heads), 4-edge batched for MLP ----------------
__global__ __launch_bounds__(256) void edgeC4_k(const int* __restrict__ rowp,
                                                const int* __restrict__ cdst,
                                                const float* __restrict__ eacsr,
                                                const float* __restrict__ S4,
                                                const ushort_t* __restrict__ ftb,
                                                ushort_t* __restrict__ lastb) {
    int node = blockIdx.x * 4 + (threadIdx.x >> 6);
    int lane = threadIdx.x & 63;
    if (node >= Nn) return;
    int h = lane >> 4;
    int r0 = rowp[node], r1 = rowp[node + 1];
    float ax = 0.f, ay = 0.f, az = 0.f, aw = 0.f;
    int i = r0;
    for (; i + 4 <= r1; i += 4) {
        int d0 = cdst[i], d1 = cdst[i + 1], d2 = cdst[i + 2], d3 = cdst[i + 3];
        float e0 = eacsr[(size_t)(i + 0) * 4 + h];
        float e1 = eacsr[(size_t)(i + 1) * 4 + h];
        float e2 = eacsr[(size_t)(i + 2) * 4 + h];
        float e3 = eacsr[(size_t)(i + 3) * 4 + h];
        float s0 = S4[d0 * 4 + h], s1 = S4[d1 * 4 + h];
        float s2 = S4[d2 * 4 + h], s3 = S4[d3 * 4 + h];
        ushort4 f0 = *(const ushort4*)(ftb + (size_t)d0 * 256 + lane * 4);
        ushort4 f1 = *(const ushort4*)(ftb + (size_t)d1 * 256 + lane * 4);
        ushort4 f2 = *(const ushort4*)(ftb + (size_t)d2 * 256 + lane * 4);
        ushort4 f3 = *(const ushort4*)(ftb + (size_t)d3 * 256 + lane * 4);
        float w0 = __fdividef(e0, s0), w1 = __fdividef(e1, s1);
        float w2 = __fdividef(e2, s2), w3 = __fdividef(e3, s3);
        ax += w0 * bf2f(f0.x) + w1 * bf2f(f1.x) + w2 * bf2f(f2.x) + w3 * bf2f(f3.x);
        ay += w0 * bf2f(f0.y) + w1 * bf2f(f1.y) + w2 * bf2f(f2.y) + w3 * bf2f(f3.y);
        az += w0 * bf2f(f0.z) + w1 * bf2f(f1.z) + w2 * bf2f(f2.z) + w3 * bf2f(f3.z);
        aw += w0 * bf2f(f0.w) + w1 * bf2f(f1.w) + w2 * bf2f(f2.w) + w3 * bf2f(f3.w);
    }
    for (; i < r1; ++i) {
        int d = cdst[i];
        float w = __fdividef(eacsr[(size_t)i * 4 + h], S4[d * 4 + h]);
        ushort4 f = *(const ushort4*)(ftb + (size_t)d * 256 + lane * 4);
        ax += w * bf2f(f.x);
        ay += w * bf2f(f.y);
        az += w * bf2f(f.z);
        aw += w * bf2f(f.w);
    }
    ax = ax > 0.f ? ax : __expf(ax) - 1.f;
    ay = ay > 0.f ? ay : __expf(ay) - 1.f;
    az = az > 0.f ? az : __expf(az) - 1.f;
    aw = aw > 0.f ? aw : __expf(aw) - 1.f;
    ushort4 o4;
    o4.x = f2bf(ax); o4.y = f2bf(ay); o4.z = f2bf(az); o4.w = f2bf(aw);
    *(ushort4*)(lastb + (size_t)node * 256 + lane * 4) = o4;
}

// ---------------- edge pass C (layer 2), 2x2 batched ----------------
__global__ __launch_bounds__(256) void edgeC1_k(const int* __restrict__ rowp,
                                                const int* __restrict__ cdst,
                                                const float* __restrict__ ea,
                                                const float* __restrict__ S2,
                                                const ushort_t* __restrict__ ftb2,
                                                float* __restrict__ outp) {
    int node = blockIdx.x * 4 + (threadIdx.x >> 6);
    int lane = threadIdx.x & 63;
    if (node >= Nn) return;
    int half = lane >> 5, l = lane & 31;
    int r0 = rowp[node], r1 = rowp[node + 1];
    float acc0 = 0.f, acc1 = 0.f;
    int i0 = r0;
    for (; i0 + 4 <= r1; i0 += 4) {
        int ia = i0 + half, ib = i0 + 2 + half;
        int da = cdst[ia], db = cdst[ib];
        float eva = ea[ia], evb = ea[ib];
        float sa = S2[da], sb = S2[db];
        ushort2 fa = *(const ushort2*)(ftb2 + (size_t)da * 64 + l * 2);
        ushort2 fb = *(const ushort2*)(ftb2 + (size_t)db * 64 + l * 2);
        float wa = __fdividef(eva, sa), wb = __fdividef(evb, sb);
        acc0 += wa * bf2f(fa.x) + wb * bf2f(fb.x);
        acc1 += wa * bf2f(fa.y) + wb * bf2f(fb.y);
    }
    for (; i0 < r1; i0 += 2) {
        int i = i0 + half;
        if (i < r1) {
            int d = cdst[i];
            float w = __fdividef(ea[i], S2[d]);
            ushort2 f = *(const ushort2*)(ftb2 + (size_t)d * 64 + l * 2);
            acc0 += w * bf2f(f.x);
            acc1 += w * bf2f(f.y);
        }
    }
    acc0 += __shfl_xor(acc0, 32);
    acc1 += __shfl_xor(acc1, 32);
    if (lane < 32) {
        *(float2*)(outp + (size_t)node * 64 + l * 2) = make_float2(acc0, acc1);
    }
}

// ---------------- launch ----------------
extern "C" void kernel_launch(void* const* d_in, const int* in_sizes, int n_in,
                              void* d_out, int out_size, void* d_ws, size_t ws_size,
                              hipStream_t stream) {
    const float* features = (const float*)d_in[0];
    const int* src = (const int*)d_in[1];
    const int* dst = (const int*)d_in[2];
    const float* W_fc = (const float*)d_in[3];
    const float* b_fc = (const float*)d_in[4];
    const float* w_al = (const float*)d_in[5];
    const float* b_al = (const float*)d_in[6];
    const float* w_ar = (const float*)d_in[7];
    const float* b_ar = (const float*)d_in[8];
    const float* W_res = (const float*)d_in[9];
    const float* b_res = (const float*)d_in[10];
    float* out = (float*)d_out;
    char* ws = (char*)d_ws;

    int* rowps = (int*)(ws + O_ROWPS);
    int* rowpd = (int*)(ws + O_ROWPD);
    int* boff = (int*)(ws + O_BOFF);
    int* gcur = (int*)(ws + O_GCUR);
    int* csr_dst = (int*)(ws + O_CSRDST);
    int* csc_src = (int*)(ws + O_CSCSRC);
    int2* bufs = (int2*)(ws + O_BUFS);
    int2* bufd = (int2*)(ws + O_BUFD);
    ushort_t* ftb1 = (ushort_t*)(ws + O_FTB1);
    ushort_t* ftb2 = (ushort_t*)(ws + O_FTB2);
    ushort_t* lastb = (ushort_t*)(ws + O_LASTB);
    float* eacsr = (float*)(ws + O_EACSR);
    float* m4 = (float*)(ws + O_M4);
    float* S4 = (float*)(ws + O_S4);
    float* a1_4 = (float*)(ws + O_A14);
    float* a2_4 = (float*)(ws + O_A24);
    float* m2 = (float*)(ws + O_M2);
    float* S2 = (float*)(ws + O_S2);
    float* a1_2 = (float*)(ws + O_A12);
    float* a2_2 = (float*)(ws + O_A22);
    float* out2 = (float*)(ws + O_OUT2);
    float* ea_l2 = (float*)(ws + O_EAL2);
    ushort_t* Wt1 = (ushort_t*)(ws + O_WT1);
    ushort_t* Wt2 = (ushort_t*)(ws + O_WT2);
    ushort_t* WtR = (ushort_t*)(ws + O_WTR);

    // ---- weight convert/transpose (tiny) ----
    wcvt_k<<<384, 256, 0, stream>>>(W_fc, W_res, Wt1, Wt2, WtR);

    // ---- graph build: bucketed counting sort ----
    hipMemsetAsync(gcur, 0, 2 * NBUCK * 4, stream);
    p3_bin_k<<<NBLK3, 256, 0, stream>>>(src, dst, gcur, bufs, bufd);
    p2_scan_k<<<2, 512, 0, stream>>>(gcur, boff, rowps, rowpd);
    p4_fill_k<<<dim3(NBUCK, 2), 256, 0, stream>>>(gcur, boff, bufs, bufd,
                                                  rowps, rowpd, csr_dst, csc_src);

    const int GB = (Nn + 127) / 128;  // 782
    const int NW = (Nn + 3) / 4;      // 25000
    // ---- layer 1: single MFMA GEMM over all 4 heads (N=256, 2 column panels) ----
    mgemm_k<0, 128, 2, 1, 0, 0, 1><<<dim3(GB, 2), 256, 0, stream>>>(
        features, nullptr, Wt1, b_fc, nullptr,
        ftb1, nullptr, 256, w_al, w_ar, b_al, b_ar, a1_4, a2_4, 4);
    maxpass4_k<<<NW, 256, 0, stream>>>(rowpd, csc_src, a1_4, a2_4, m4);
    sumpass4_k<<<NW, 256, 0, stream>>>(rowps, csr_dst, a1_4, a2_4, m4, eacsr, S4);
    edgeC4_k<<<NW, 256, 0, stream>>>(rowps, csr_dst, eacsr, S4, ftb1, lastb);

    // ---- layer 2: head 4 (A = lastb bf16) ----
    mgemm_k<1, 64, 4, 1, 0, 0, 1><<<dim3(GB, 1), 256, 0, stream>>>(
        nullptr, lastb, Wt2, b_fc + 256, nullptr,
        ftb2, nullptr, 64, w_al + 256, w_ar + 256, b_al + 4, b_ar + 4,
        a1_2, a2_2, 1);
    maxpass1_k<<<NW, 256, 0, stream>>>(rowpd, csc_src, a1_2, a2_2, m2);
    sumpass1_k<<<NW, 256, 0, stream>>>(rowps, csr_dst, a1_2, a2_2, m2, ea_l2, S2);
    edgeC1_k<<<NW, 256, 0, stream>>>(rowps, csr_dst, ea_l2, S2, ftb2, out2);

    // ---- final: elu(lastb @ WtR^T + b_res + out2) -> f32 out ----
    mgemm_k<1, 64, 4, 0, 1, 1, 0><<<dim3(GB, 1), 256, 0, stream>>>(
        nullptr, lastb, WtR, b_res, out2,
        nullptr, out, 64, nullptr, nullptr, nullptr, nullptr, nullptr, nullptr, 0);
}